// Round 2
// baseline (5025.410 us; speedup 1.0000x reference)
//
#include <hip/hip_runtime.h>
#include <stdint.h>

#define T_LEN 64
#define B_SZ  128
#define H_SZ  768
#define G_SZ  3072
#define E_SZ  768
#define LN_EPS 1e-5f

typedef __bf16 bf16x8 __attribute__((ext_vector_type(8)));
typedef float  f32x4  __attribute__((ext_vector_type(4)));
typedef short  short8 __attribute__((ext_vector_type(8)));

__device__ __forceinline__ float bf2f(unsigned short h) {
  unsigned int u = ((unsigned int)h) << 16;
  return __builtin_bit_cast(float, u);
}
__device__ __forceinline__ unsigned short f2bf(float f) {
  unsigned int u = __builtin_bit_cast(unsigned int, f);
  u += 0x7fffu + ((u >> 16) & 1u);   // RNE
  return (unsigned short)(u >> 16);
}
// split 8 floats into hi/lo bf16 (double-bf16 decomposition)
__device__ __forceinline__ void split8(float4 v0, float4 v1, short8& hi, short8& lo) {
  float v[8] = {v0.x, v0.y, v0.z, v0.w, v1.x, v1.y, v1.z, v1.w};
#pragma unroll
  for (int j = 0; j < 8; ++j) {
    unsigned short h = f2bf(v[j]);
    hi[j] = (short)h;
    lo[j] = (short)f2bf(v[j] - bf2f(h));
  }
}

// ---------------------------------------------------------------------------
// Prep: gather embeddings -> hi/lo bf16 planes, split layer-1 weights,
// fold biases, zero h-state planes / stats / barrier counters.
// ---------------------------------------------------------------------------
__global__ void prep_kernel(const int* __restrict__ msg,
                            const float* __restrict__ table,
                            const float* __restrict__ W_ih,
                            const float* __restrict__ W_hh,
                            const float* __restrict__ b_ih,
                            const float* __restrict__ b_hh,
                            unsigned short* __restrict__ A_hi,
                            unsigned short* __restrict__ A_lo,
                            unsigned short* __restrict__ Wih_hi,
                            unsigned short* __restrict__ Wih_lo,
                            unsigned short* __restrict__ Whh_hi,
                            unsigned short* __restrict__ Whh_lo,
                            float* __restrict__ bias,
                            unsigned short* __restrict__ Hhi,
                            unsigned short* __restrict__ Hlo,
                            float* __restrict__ stats,
                            unsigned int* __restrict__ bar) {
  int idx = blockIdx.x * blockDim.x + threadIdx.x;
  int stride = gridDim.x * blockDim.x;
  // Embedding gather (8192 rows x 96 chunks of 8 floats), n = t*128+b
  for (int c = idx; c < 8192 * 96; c += stride) {
    int n = c / 96;
    int ko = (c - n * 96) * 8;
    int b = n & 127, t = n >> 7;
    int m = msg[b * T_LEN + t];
    const float4* s4 = (const float4*)(table + (size_t)m * E_SZ + ko);
    short8 hi, lo;
    split8(s4[0], s4[1], hi, lo);
    *(short8*)(A_hi + (size_t)n * E_SZ + ko) = hi;
    *(short8*)(A_lo + (size_t)n * E_SZ + ko) = lo;
  }
  // Layer-1 weight split (offset G*E into (L,G,E)/(L,G,H))
  for (int c = idx; c < G_SZ * E_SZ / 8; c += stride) {
    int o8 = c * 8;
    {
      const float4* s4 = (const float4*)(W_ih + (size_t)G_SZ * E_SZ + o8);
      short8 hi, lo;
      split8(s4[0], s4[1], hi, lo);
      *(short8*)(Wih_hi + o8) = hi;
      *(short8*)(Wih_lo + o8) = lo;
    }
    {
      const float4* s4 = (const float4*)(W_hh + (size_t)G_SZ * H_SZ + o8);
      short8 hi, lo;
      split8(s4[0], s4[1], hi, lo);
      *(short8*)(Whh_hi + o8) = hi;
      *(short8*)(Whh_lo + o8) = lo;
    }
  }
  for (int c = idx; c < G_SZ; c += stride) bias[c] = b_ih[G_SZ + c] + b_hh[G_SZ + c];
  for (int c = idx; c < B_SZ * H_SZ / 2; c += stride) {
    ((unsigned int*)Hhi)[c] = 0u;
    ((unsigned int*)Hlo)[c] = 0u;
  }
  for (int c = idx; c < T_LEN * B_SZ * 4; c += stride) stats[c] = 0.f;
  for (int c = idx; c < 1152; c += stride) bar[c] = 0u;
}

// ---------------------------------------------------------------------------
// Phase 1: X[t][g][b] = A . Wih^T + bias, double-bf16 (3-term) MFMA,
// 64x64 tile, BK=32, hi/lo staged in 4 LDS planes.
// ---------------------------------------------------------------------------
#define K2_STR 56   // padded LDS stride (elements): 112B, bank period 8 (2-way free)

__global__ __launch_bounds__(256) void xproj_kernel(
    const unsigned short* __restrict__ A_hi, const unsigned short* __restrict__ A_lo,
    const unsigned short* __restrict__ B_hi, const unsigned short* __restrict__ B_lo,
    const float* __restrict__ bias, void* __restrict__ Xout, int x_is_f32) {
  __shared__ float smemf[7168];  // 28672 B: 4 staging planes; epilogue Cs overlaps
  unsigned short* AsH = (unsigned short*)smemf;
  unsigned short* AsL = AsH + 64 * K2_STR;
  unsigned short* BsH = AsL + 64 * K2_STR;
  unsigned short* BsL = BsH + 64 * K2_STR;

  // swizzle: 16 chunks of 8 mb x 48 nb -> a 384-block window reuses 8 A-panels
  int bid = blockIdx.x;
  int mchunk = bid / 384;
  int r = bid - mchunk * 384;
  int nb = r >> 3;
  int mb = (mchunk << 3) + (r & 7);
  int m0 = mb * 64, n0 = nb * 64;
  int tid = threadIdx.x;
  int w = tid >> 6, lane = tid & 63;
  int wm = w & 1, wn = w >> 1;
  int rs = tid >> 2, ks = (tid & 3) * 8;
  int lrow = lane & 15, lk = (lane >> 4) * 8;

  f32x4 acc[2][2] = {};
  const unsigned short* gA = A_hi + (size_t)(m0 + rs) * E_SZ + ks;
  const unsigned short* gAl = A_lo + (size_t)(m0 + rs) * E_SZ + ks;
  const unsigned short* gB = B_hi + (size_t)(n0 + rs) * E_SZ + ks;
  const unsigned short* gBl = B_lo + (size_t)(n0 + rs) * E_SZ + ks;
  short8 vah = *(const short8*)gA;
  short8 val = *(const short8*)gAl;
  short8 vbh = *(const short8*)gB;
  short8 vbl = *(const short8*)gBl;
  for (int kt = 0; kt < 24; ++kt) {
    __syncthreads();
    *(short8*)(AsH + rs * K2_STR + ks) = vah;
    *(short8*)(AsL + rs * K2_STR + ks) = val;
    *(short8*)(BsH + rs * K2_STR + ks) = vbh;
    *(short8*)(BsL + rs * K2_STR + ks) = vbl;
    __syncthreads();
    if (kt < 23) {
      int k0 = (kt + 1) * 32;
      vah = *(const short8*)(gA + k0);
      val = *(const short8*)(gAl + k0);
      vbh = *(const short8*)(gB + k0);
      vbl = *(const short8*)(gBl + k0);
    }
    bf16x8 ah0 = *(const bf16x8*)(AsH + (wm * 32 +      lrow) * K2_STR + lk);
    bf16x8 ah1 = *(const bf16x8*)(AsH + (wm * 32 + 16 + lrow) * K2_STR + lk);
    bf16x8 al0 = *(const bf16x8*)(AsL + (wm * 32 +      lrow) * K2_STR + lk);
    bf16x8 al1 = *(const bf16x8*)(AsL + (wm * 32 + 16 + lrow) * K2_STR + lk);
    bf16x8 bh0 = *(const bf16x8*)(BsH + (wn * 32 +      lrow) * K2_STR + lk);
    bf16x8 bh1 = *(const bf16x8*)(BsH + (wn * 32 + 16 + lrow) * K2_STR + lk);
    bf16x8 bl0 = *(const bf16x8*)(BsL + (wn * 32 +      lrow) * K2_STR + lk);
    bf16x8 bl1 = *(const bf16x8*)(BsL + (wn * 32 + 16 + lrow) * K2_STR + lk);
    acc[0][0] = __builtin_amdgcn_mfma_f32_16x16x32_bf16(ah0, bh0, acc[0][0], 0, 0, 0);
    acc[1][0] = __builtin_amdgcn_mfma_f32_16x16x32_bf16(ah1, bh0, acc[1][0], 0, 0, 0);
    acc[0][1] = __builtin_amdgcn_mfma_f32_16x16x32_bf16(ah0, bh1, acc[0][1], 0, 0, 0);
    acc[1][1] = __builtin_amdgcn_mfma_f32_16x16x32_bf16(ah1, bh1, acc[1][1], 0, 0, 0);
    acc[0][0] = __builtin_amdgcn_mfma_f32_16x16x32_bf16(al0, bh0, acc[0][0], 0, 0, 0);
    acc[1][0] = __builtin_amdgcn_mfma_f32_16x16x32_bf16(al1, bh0, acc[1][0], 0, 0, 0);
    acc[0][1] = __builtin_amdgcn_mfma_f32_16x16x32_bf16(al0, bh1, acc[0][1], 0, 0, 0);
    acc[1][1] = __builtin_amdgcn_mfma_f32_16x16x32_bf16(al1, bh1, acc[1][1], 0, 0, 0);
    acc[0][0] = __builtin_amdgcn_mfma_f32_16x16x32_bf16(ah0, bl0, acc[0][0], 0, 0, 0);
    acc[1][0] = __builtin_amdgcn_mfma_f32_16x16x32_bf16(ah1, bl0, acc[1][0], 0, 0, 0);
    acc[0][1] = __builtin_amdgcn_mfma_f32_16x16x32_bf16(ah0, bl1, acc[0][1], 0, 0, 0);
    acc[1][1] = __builtin_amdgcn_mfma_f32_16x16x32_bf16(ah1, bl1, acc[1][1], 0, 0, 0);
  }
  __syncthreads();
  // transpose via LDS: Cs[n][m], stride 72
  float* Cs = smemf;
  int quad = lane >> 4;
#pragma unroll
  for (int mt = 0; mt < 2; ++mt)
#pragma unroll
    for (int nt = 0; nt < 2; ++nt) {
      int mloc = wm * 32 + mt * 16 + quad * 4;
      int nloc = wn * 32 + nt * 16 + lrow;
#pragma unroll
      for (int rr = 0; rr < 4; ++rr) Cs[nloc * 72 + mloc + rr] = acc[mt][nt][rr];
    }
  __syncthreads();
  int t = mb >> 1, bbase = (mb & 1) * 64;
#pragma unroll
  for (int rep = 0; rep < 2; ++rep) {
    int n = (tid >> 3) + rep * 32;
    int c = (tid & 7) * 8;
    float bv = bias[n0 + n];
    float v[8];
#pragma unroll
    for (int j = 0; j < 8; ++j) v[j] = Cs[n * 72 + c + j] + bv;
    size_t off = ((size_t)t * G_SZ + (n0 + n)) * B_SZ + bbase + c;
    if (x_is_f32) {
      float4* dst = (float4*)((float*)Xout + off);
      dst[0] = make_float4(v[0], v[1], v[2], v[3]);
      dst[1] = make_float4(v[4], v[5], v[6], v[7]);
    } else {
      short8 o;
#pragma unroll
      for (int j = 0; j < 8; ++j) o[j] = (short)f2bf(v[j]);
      *(short8*)((unsigned short*)Xout + off) = o;
    }
  }
}

// ---------------------------------------------------------------------------
// Phase 2: cooperative LSTM recurrence. 384 WGs = 96 j-blocks x 4 row-blocks.
// W_hh hi persistent in LDS; W_hh lo streamed from L2; h-state hi/lo global.
// ---------------------------------------------------------------------------
__device__ __forceinline__ void gridbar(unsigned int* leaf, unsigned int* root,
                                        int idx, int group) {
  __syncthreads();
  if (threadIdx.x == 0) {
    unsigned int old = __hip_atomic_fetch_add(&leaf[idx * 8 + group], 1u,
                                              __ATOMIC_ACQ_REL, __HIP_MEMORY_SCOPE_AGENT);
    if (old == 47u)
      __hip_atomic_fetch_add(&root[idx], 1u, __ATOMIC_ACQ_REL, __HIP_MEMORY_SCOPE_AGENT);
    while (__hip_atomic_load(&root[idx], __ATOMIC_ACQUIRE, __HIP_MEMORY_SCOPE_AGENT) < 8u)
      __builtin_amdgcn_s_sleep(1);
  }
  __syncthreads();
}

__global__ __launch_bounds__(128) void lstm_kernel(
    const unsigned short* __restrict__ Whh_hi, const unsigned short* __restrict__ Whh_lo,
    const void* __restrict__ X, int x_is_f32,
    const float* __restrict__ gamma_h, const float* __restrict__ beta_h,
    const float* __restrict__ gamma_c, const float* __restrict__ beta_c,
    const int* __restrict__ lens,
    unsigned short* __restrict__ Hhi, unsigned short* __restrict__ Hlo,
    float* __restrict__ stats,
    unsigned int* __restrict__ bar, float* __restrict__ out) {
  __shared__ unsigned short Wt[32 * 776];   // 49664 B, stride 776 (bank period 8)
  __shared__ float glds[4][32][8];          // gate pre-activations / cpre,hpre
  __shared__ float cst[32][8];              // c state
  __shared__ float rstat[32][4];            // row partial sums / broadcast stats
  __shared__ float gh[8], bh[8], gc[8], bc[8];

  int bidx = blockIdx.x;
  int jb = bidx % 96, rb = bidx / 96;
  int j0 = jb * 8, b0 = rb * 32;
  int tid = threadIdx.x;
  int w = tid >> 6, lane = tid & 63;
  int lrow = lane & 15, lkq = lane >> 4;
  int group = bidx & 7;
  unsigned int* leaf = bar;
  unsigned int* root = bar + 1024;

  // load persistent W_hi slice: LDS row r <-> gate r>>3, jj r&7
  for (int c = tid; c < 3072; c += 128) {
    int row = c / 96, ko = (c - row * 96) * 8;
    short8 v = *(const short8*)(Whh_hi +
        ((size_t)((row >> 3) * H_SZ + j0 + (row & 7))) * H_SZ + ko);
    *(short8*)(&Wt[row * 776 + ko]) = v;
  }
  if (tid < 8) {
    gh[tid] = gamma_h[j0 + tid]; bh[tid] = beta_h[j0 + tid];
    gc[tid] = gamma_c[j0 + tid]; bc[tid] = beta_c[j0 + tid];
  }
  for (int c = tid; c < 256; c += 128) cst[c >> 3][c & 7] = 0.f;

  int myrow = tid & 31;          // batch row this thread finalizes
  int jjA = tid >> 5;            // jj pair: jjA and jjA+4
  int mylen = lens[b0 + myrow];
  const unsigned short* h0h = Hhi + (size_t)(b0 + lrow) * H_SZ;
  const unsigned short* h0l = Hlo + (size_t)(b0 + lrow) * H_SZ;
  const unsigned short* h1h = Hhi + (size_t)(b0 + 16 + lrow) * H_SZ;
  const unsigned short* h1l = Hlo + (size_t)(b0 + 16 + lrow) * H_SZ;
  int myWrow = (w << 4) | lrow;   // 0..31 (this wave's gate-row for MFMA B)
  const unsigned short* wbase = &Wt[myWrow * 776];
  const unsigned short* wlo_base = Whh_lo +
      (size_t)((myWrow >> 3) * H_SZ + j0 + (myWrow & 7)) * H_SZ;
  __syncthreads();

  for (int t = 0; t < T_LEN; ++t) {
    // ---- gates GEMM: acc = h . W^T, 3-term double-bf16
    f32x4 acc0 = {}, acc1 = {};
#pragma unroll 4
    for (int kt = 0; kt < 24; ++kt) {
      int k0 = kt * 32 + lkq * 8;
      bf16x8 wh = *(const bf16x8*)(wbase + k0);
      bf16x8 wl = *(const bf16x8*)(wlo_base + k0);
      bf16x8 a0h = *(const bf16x8*)(h0h + k0);
      bf16x8 a0l = *(const bf16x8*)(h0l + k0);
      bf16x8 a1h = *(const bf16x8*)(h1h + k0);
      bf16x8 a1l = *(const bf16x8*)(h1l + k0);
      acc0 = __builtin_amdgcn_mfma_f32_16x16x32_bf16(a0h, wh, acc0, 0, 0, 0);
      acc1 = __builtin_amdgcn_mfma_f32_16x16x32_bf16(a1h, wh, acc1, 0, 0, 0);
      acc0 = __builtin_amdgcn_mfma_f32_16x16x32_bf16(a0l, wh, acc0, 0, 0, 0);
      acc1 = __builtin_amdgcn_mfma_f32_16x16x32_bf16(a1l, wh, acc1, 0, 0, 0);
      acc0 = __builtin_amdgcn_mfma_f32_16x16x32_bf16(a0h, wl, acc0, 0, 0, 0);
      acc1 = __builtin_amdgcn_mfma_f32_16x16x32_bf16(a1h, wl, acc1, 0, 0, 0);
    }
    // ---- add X and write gate pre-acts to LDS
    {
      int gate = w * 2 + (lrow >> 3);
      int jj = lrow & 7;
      size_t xrow = (size_t)t * G_SZ + (size_t)gate * H_SZ + j0 + jj;
#pragma unroll
      for (int mt = 0; mt < 2; ++mt) {
        int rowb = mt * 16 + lkq * 4;
        f32x4 a = mt ? acc1 : acc0;
        float xv0, xv1, xv2, xv3;
        if (x_is_f32) {
          float4 x4 = *(const float4*)((const float*)X + xrow * B_SZ + b0 + rowb);
          xv0 = x4.x; xv1 = x4.y; xv2 = x4.z; xv3 = x4.w;
        } else {
          ushort4 x4 = *(const ushort4*)((const unsigned short*)X + xrow * B_SZ + b0 + rowb);
          xv0 = bf2f(x4.x); xv1 = bf2f(x4.y); xv2 = bf2f(x4.z); xv3 = bf2f(x4.w);
        }
        glds[gate][rowb + 0][jj] = a[0] + xv0;
        glds[gate][rowb + 1][jj] = a[1] + xv1;
        glds[gate][rowb + 2][jj] = a[2] + xv2;
        glds[gate][rowb + 3][jj] = a[3] + xv3;
      }
    }
    rstat[tid >> 2][tid & 3] = 0.f;
    __syncthreads();
    // ---- LSTM cell (2 jj per thread, same row)
#pragma unroll
    for (int p = 0; p < 2; ++p) {
      int jj = jjA + p * 4;
      float iv = glds[0][myrow][jj], fv = glds[1][myrow][jj];
      float gv = glds[2][myrow][jj], ov = glds[3][myrow][jj];
      float si = 1.f / (1.f + expf(-iv));
      float sf = 1.f / (1.f + expf(-fv));
      float so = 1.f / (1.f + expf(-ov));
      float cn = sf * cst[myrow][jj] + si * tanhf(gv);
      float hp = so * tanhf(cn);
      glds[0][myrow][jj] = cn;   // c_pre
      glds[1][myrow][jj] = hp;   // h_pre
      atomicAdd(&rstat[myrow][0], hp);
      atomicAdd(&rstat[myrow][1], hp * hp);
      atomicAdd(&rstat[myrow][2], cn);
      atomicAdd(&rstat[myrow][3], cn * cn);
    }
    __syncthreads();
    // ---- push partial stats, global barrier A, read totals back
    {
      int row = tid >> 2, s = tid & 3;
      atomicAdd(&stats[((size_t)t * B_SZ + b0 + row) * 4 + s], rstat[row][s]);
    }
    gridbar(leaf, root, 2 * t, group);
    {
      int row = tid >> 2, s = tid & 3;
      rstat[row][s] = stats[((size_t)t * B_SZ + b0 + row) * 4 + s];
    }
    __syncthreads();
    // ---- finalize LayerNorms, write h state hi/lo (+output at t == len-1)
    {
      float muh = rstat[myrow][0] * (1.f / 768.f);
      float muc = rstat[myrow][2] * (1.f / 768.f);
      float vh = rstat[myrow][1] * (1.f / 768.f) - muh * muh;
      float vc = rstat[myrow][3] * (1.f / 768.f) - muc * muc;
      float rh = rsqrtf(vh + LN_EPS), rc = rsqrtf(vc + LN_EPS);
#pragma unroll
      for (int p = 0; p < 2; ++p) {
        int jj = jjA + p * 4;
        float cn = glds[0][myrow][jj], hp = glds[1][myrow][jj];
        float hout = (hp - muh) * rh * gh[jj] + bh[jj];
        float cout = (cn - muc) * rc * gc[jj] + bc[jj];
        cst[myrow][jj] = cout;
        size_t hidx = (size_t)(b0 + myrow) * H_SZ + j0 + jj;
        unsigned short hh = f2bf(hout);
        Hhi[hidx] = hh;
        Hlo[hidx] = f2bf(hout - bf2f(hh));
        if (t == mylen - 1) out[hidx] = hout;
      }
    }
    gridbar(leaf, root, 2 * t + 1, group);
  }
}

// ---------------------------------------------------------------------------
extern "C" void kernel_launch(void* const* d_in, const int* in_sizes, int n_in,
                              void* d_out, int out_size, void* d_ws, size_t ws_size,
                              hipStream_t stream) {
  const int*   msg     = (const int*)d_in[0];
  const int*   lens    = (const int*)d_in[1];
  const float* table   = (const float*)d_in[2];
  const float* W_ih    = (const float*)d_in[3];
  const float* W_hh    = (const float*)d_in[4];
  const float* b_ih    = (const float*)d_in[5];
  const float* b_hh    = (const float*)d_in[6];
  const float* gamma_h = (const float*)d_in[7];
  const float* beta_h  = (const float*)d_in[8];
  const float* gamma_c = (const float*)d_in[9];
  const float* beta_c  = (const float*)d_in[10];
  float* out = (float*)d_out;

  size_t szA = (size_t)8192 * 768 * 2;
  size_t szW = (size_t)3072 * 768 * 2;
  size_t szBias = 3072 * 4;
  size_t szH = (size_t)128 * 768 * 2;
  size_t szStats = (size_t)64 * 128 * 4 * 4;
  size_t szBar = 1152 * 4;
  size_t rest = 2 * szA + 4 * szW + szBias + 2 * szH + szStats + szBar;
  size_t xf32 = (size_t)64 * 3072 * 128 * 4;
  int x_is_f32 = (ws_size >= xf32 + rest) ? 1 : 0;

  char* p = (char*)d_ws;
  void* X = (void*)p;               p += x_is_f32 ? xf32 : (xf32 / 2);
  unsigned short* A_hi   = (unsigned short*)p; p += szA;
  unsigned short* A_lo   = (unsigned short*)p; p += szA;
  unsigned short* Wih_hi = (unsigned short*)p; p += szW;
  unsigned short* Wih_lo = (unsigned short*)p; p += szW;
  unsigned short* Whh_hi = (unsigned short*)p; p += szW;
  unsigned short* Whh_lo = (unsigned short*)p; p += szW;
  float* bias = (float*)p;          p += szBias;
  unsigned short* Hhi = (unsigned short*)p; p += szH;
  unsigned short* Hlo = (unsigned short*)p; p += szH;
  float* stats = (float*)p;         p += szStats;
  unsigned int* bar = (unsigned int*)p;     p += szBar;

  hipLaunchKernelGGL(prep_kernel, dim3(1024), dim3(256), 0, stream,
                     msg, table, W_ih, W_hh, b_ih, b_hh,
                     A_hi, A_lo, Wih_hi, Wih_lo, Whh_hi, Whh_lo, bias,
                     Hhi, Hlo, stats, bar);
  hipLaunchKernelGGL(xproj_kernel, dim3(6144), dim3(256), 0, stream,
                     A_hi, A_lo, Wih_hi, Wih_lo, bias, X, x_is_f32);

  void* kargs[] = { (void*)&Whh_hi, (void*)&Whh_lo, (void*)&X, (void*)&x_is_f32,
                    (void*)&gamma_h, (void*)&beta_h, (void*)&gamma_c, (void*)&beta_c,
                    (void*)&lens, (void*)&Hhi, (void*)&Hlo, (void*)&stats,
                    (void*)&bar, (void*)&out };
  hipLaunchCooperativeKernel((void*)lstm_kernel, dim3(384), dim3(128), kargs, 0, stream);
}

// Round 3
// 3883.853 us; speedup vs baseline: 1.2939x; 1.2939x over previous
//
#include <hip/hip_runtime.h>
#include <stdint.h>

#define T_LEN 64
#define B_SZ  128
#define H_SZ  768
#define G_SZ  3072
#define E_SZ  768
#define LN_EPS 1e-5f
#define HPL   (128 * 768)   // one h-plane (elements)

typedef __bf16 bf16x8 __attribute__((ext_vector_type(8)));
typedef float  f32x4  __attribute__((ext_vector_type(4)));
typedef short  short8 __attribute__((ext_vector_type(8)));

__device__ __forceinline__ float bf2f(unsigned short h) {
  unsigned int u = ((unsigned int)h) << 16;
  return __builtin_bit_cast(float, u);
}
__device__ __forceinline__ unsigned short f2bf(float f) {
  unsigned int u = __builtin_bit_cast(unsigned int, f);
  u += 0x7fffu + ((u >> 16) & 1u);   // RNE
  return (unsigned short)(u >> 16);
}
__device__ __forceinline__ void split8(float4 v0, float4 v1, short8& hi, short8& lo) {
  float v[8] = {v0.x, v0.y, v0.z, v0.w, v1.x, v1.y, v1.z, v1.w};
#pragma unroll
  for (int j = 0; j < 8; ++j) {
    unsigned short h = f2bf(v[j]);
    hi[j] = (short)h;
    lo[j] = (short)f2bf(v[j] - bf2f(h));
  }
}
__device__ __forceinline__ float pick4(int k, float v0, float v1, float v2, float v3) {
  return k == 0 ? v0 : k == 1 ? v1 : k == 2 ? v2 : v3;
}

// ---------------------------------------------------------------------------
// Prep: embeddings -> hi/lo bf16; Wih split; Whh' = (gamma_h (.) Whh) split;
// SW'[g], Sbeta[g]; bias = b_ih+b_hh; zero h planes & barrier counters.
// ---------------------------------------------------------------------------
__global__ void prep_kernel(const int* __restrict__ msg,
                            const float* __restrict__ table,
                            const float* __restrict__ W_ih,
                            const float* __restrict__ W_hh,
                            const float* __restrict__ b_ih,
                            const float* __restrict__ b_hh,
                            const float* __restrict__ gamma_h,
                            const float* __restrict__ beta_h,
                            unsigned short* __restrict__ A_hi,
                            unsigned short* __restrict__ A_lo,
                            unsigned short* __restrict__ Wih_hi,
                            unsigned short* __restrict__ Wih_lo,
                            unsigned short* __restrict__ Whh_hi,
                            unsigned short* __restrict__ Whh_lo,
                            float* __restrict__ SWp,
                            float* __restrict__ Sbeta,
                            float* __restrict__ bias,
                            unsigned short* __restrict__ Hhi,
                            unsigned short* __restrict__ Hlo,
                            unsigned int* __restrict__ bar) {
  int idx = blockIdx.x * blockDim.x + threadIdx.x;
  int stride = gridDim.x * blockDim.x;
  // Embedding gather, n = t*128+b
  for (int c = idx; c < 8192 * 96; c += stride) {
    int n = c / 96;
    int ko = (c - n * 96) * 8;
    int b = n & 127, t = n >> 7;
    int m = msg[b * T_LEN + t];
    const float4* s4 = (const float4*)(table + (size_t)m * E_SZ + ko);
    short8 hi, lo;
    split8(s4[0], s4[1], hi, lo);
    *(short8*)(A_hi + (size_t)n * E_SZ + ko) = hi;
    *(short8*)(A_lo + (size_t)n * E_SZ + ko) = lo;
  }
  // Layer-1 weight splits (layer offset G*E / G*H). Whh scaled by gamma_h[j].
  for (int c = idx; c < G_SZ * E_SZ / 8; c += stride) {
    int o8 = c * 8;
    {
      const float4* s4 = (const float4*)(W_ih + (size_t)G_SZ * E_SZ + o8);
      short8 hi, lo;
      split8(s4[0], s4[1], hi, lo);
      *(short8*)(Wih_hi + o8) = hi;
      *(short8*)(Wih_lo + o8) = lo;
    }
    {
      int g = o8 / H_SZ;
      int j = o8 - g * H_SZ;
      const float4* s4 = (const float4*)(W_hh + (size_t)G_SZ * H_SZ + o8);
      const float4* g4 = (const float4*)(gamma_h + j);
      float4 v0 = s4[0], v1 = s4[1];
      float4 w0 = g4[0], w1 = g4[1];
      v0.x *= w0.x; v0.y *= w0.y; v0.z *= w0.z; v0.w *= w0.w;
      v1.x *= w1.x; v1.y *= w1.y; v1.z *= w1.z; v1.w *= w1.w;
      short8 hi, lo;
      split8(v0, v1, hi, lo);
      *(short8*)(Whh_hi + o8) = hi;
      *(short8*)(Whh_lo + o8) = lo;
    }
  }
  // SW'[g] = sum_j gamma_h[j]*W[g][j], Sbeta[g] = sum_j beta_h[j]*W[g][j]
  for (int g = idx; g < G_SZ; g += stride) {
    const float4* wr = (const float4*)(W_hh + (size_t)G_SZ * H_SZ + (size_t)g * H_SZ);
    const float4* gm = (const float4*)gamma_h;
    const float4* bt = (const float4*)beta_h;
    float sw = 0.f, sb = 0.f;
    for (int i = 0; i < H_SZ / 4; ++i) {
      float4 wv = wr[i], gv = gm[i], bv = bt[i];
      sw += wv.x * gv.x + wv.y * gv.y + wv.z * gv.z + wv.w * gv.w;
      sb += wv.x * bv.x + wv.y * bv.y + wv.z * bv.z + wv.w * bv.w;
    }
    SWp[g] = sw;
    Sbeta[g] = sb;
    bias[g] = b_ih[G_SZ + g] + b_hh[G_SZ + g];
  }
  for (int c = idx; c < 2 * HPL / 2; c += stride) {
    ((unsigned int*)Hhi)[c] = 0u;
    ((unsigned int*)Hlo)[c] = 0u;
  }
  for (int c = idx; c < 2304; c += stride) bar[c] = 0u;
}

// ---------------------------------------------------------------------------
// Phase 1: X[t][g][b] = A . Wih^T + bias (3-term double-bf16 MFMA)
// ---------------------------------------------------------------------------
#define K2_STR 56

__global__ __launch_bounds__(256) void xproj_kernel(
    const unsigned short* __restrict__ A_hi, const unsigned short* __restrict__ A_lo,
    const unsigned short* __restrict__ B_hi, const unsigned short* __restrict__ B_lo,
    const float* __restrict__ bias, void* __restrict__ Xout, int x_is_f32) {
  __shared__ float smemf[7168];
  unsigned short* AsH = (unsigned short*)smemf;
  unsigned short* AsL = AsH + 64 * K2_STR;
  unsigned short* BsH = AsL + 64 * K2_STR;
  unsigned short* BsL = BsH + 64 * K2_STR;

  int bid = blockIdx.x;
  int mchunk = bid / 384;
  int r = bid - mchunk * 384;
  int nb = r >> 3;
  int mb = (mchunk << 3) + (r & 7);
  int m0 = mb * 64, n0 = nb * 64;
  int tid = threadIdx.x;
  int w = tid >> 6, lane = tid & 63;
  int wm = w & 1, wn = w >> 1;
  int rs = tid >> 2, ks = (tid & 3) * 8;
  int lrow = lane & 15, lk = (lane >> 4) * 8;

  f32x4 acc[2][2] = {};
  const unsigned short* gA = A_hi + (size_t)(m0 + rs) * E_SZ + ks;
  const unsigned short* gAl = A_lo + (size_t)(m0 + rs) * E_SZ + ks;
  const unsigned short* gB = B_hi + (size_t)(n0 + rs) * E_SZ + ks;
  const unsigned short* gBl = B_lo + (size_t)(n0 + rs) * E_SZ + ks;
  short8 vah = *(const short8*)gA;
  short8 val = *(const short8*)gAl;
  short8 vbh = *(const short8*)gB;
  short8 vbl = *(const short8*)gBl;
  for (int kt = 0; kt < 24; ++kt) {
    __syncthreads();
    *(short8*)(AsH + rs * K2_STR + ks) = vah;
    *(short8*)(AsL + rs * K2_STR + ks) = val;
    *(short8*)(BsH + rs * K2_STR + ks) = vbh;
    *(short8*)(BsL + rs * K2_STR + ks) = vbl;
    __syncthreads();
    if (kt < 23) {
      int k0 = (kt + 1) * 32;
      vah = *(const short8*)(gA + k0);
      val = *(const short8*)(gAl + k0);
      vbh = *(const short8*)(gB + k0);
      vbl = *(const short8*)(gBl + k0);
    }
    bf16x8 ah0 = *(const bf16x8*)(AsH + (wm * 32 +      lrow) * K2_STR + lk);
    bf16x8 ah1 = *(const bf16x8*)(AsH + (wm * 32 + 16 + lrow) * K2_STR + lk);
    bf16x8 al0 = *(const bf16x8*)(AsL + (wm * 32 +      lrow) * K2_STR + lk);
    bf16x8 al1 = *(const bf16x8*)(AsL + (wm * 32 + 16 + lrow) * K2_STR + lk);
    bf16x8 bh0 = *(const bf16x8*)(BsH + (wn * 32 +      lrow) * K2_STR + lk);
    bf16x8 bh1 = *(const bf16x8*)(BsH + (wn * 32 + 16 + lrow) * K2_STR + lk);
    bf16x8 bl0 = *(const bf16x8*)(BsL + (wn * 32 +      lrow) * K2_STR + lk);
    bf16x8 bl1 = *(const bf16x8*)(BsL + (wn * 32 + 16 + lrow) * K2_STR + lk);
    acc[0][0] = __builtin_amdgcn_mfma_f32_16x16x32_bf16(ah0, bh0, acc[0][0], 0, 0, 0);
    acc[1][0] = __builtin_amdgcn_mfma_f32_16x16x32_bf16(ah1, bh0, acc[1][0], 0, 0, 0);
    acc[0][1] = __builtin_amdgcn_mfma_f32_16x16x32_bf16(ah0, bh1, acc[0][1], 0, 0, 0);
    acc[1][1] = __builtin_amdgcn_mfma_f32_16x16x32_bf16(ah1, bh1, acc[1][1], 0, 0, 0);
    acc[0][0] = __builtin_amdgcn_mfma_f32_16x16x32_bf16(al0, bh0, acc[0][0], 0, 0, 0);
    acc[1][0] = __builtin_amdgcn_mfma_f32_16x16x32_bf16(al1, bh0, acc[1][0], 0, 0, 0);
    acc[0][1] = __builtin_amdgcn_mfma_f32_16x16x32_bf16(al0, bh1, acc[0][1], 0, 0, 0);
    acc[1][1] = __builtin_amdgcn_mfma_f32_16x16x32_bf16(al1, bh1, acc[1][1], 0, 0, 0);
    acc[0][0] = __builtin_amdgcn_mfma_f32_16x16x32_bf16(ah0, bl0, acc[0][0], 0, 0, 0);
    acc[1][0] = __builtin_amdgcn_mfma_f32_16x16x32_bf16(ah1, bl0, acc[1][0], 0, 0, 0);
    acc[0][1] = __builtin_amdgcn_mfma_f32_16x16x32_bf16(ah0, bl1, acc[0][1], 0, 0, 0);
    acc[1][1] = __builtin_amdgcn_mfma_f32_16x16x32_bf16(ah1, bl1, acc[1][1], 0, 0, 0);
  }
  __syncthreads();
  float* Cs = smemf;
  int quad = lane >> 4;
#pragma unroll
  for (int mt = 0; mt < 2; ++mt)
#pragma unroll
    for (int nt = 0; nt < 2; ++nt) {
      int mloc = wm * 32 + mt * 16 + quad * 4;
      int nloc = wn * 32 + nt * 16 + lrow;
#pragma unroll
      for (int rr = 0; rr < 4; ++rr) Cs[nloc * 72 + mloc + rr] = acc[mt][nt][rr];
    }
  __syncthreads();
  int t = mb >> 1, bbase = (mb & 1) * 64;
#pragma unroll
  for (int rep = 0; rep < 2; ++rep) {
    int n = (tid >> 3) + rep * 32;
    int c = (tid & 7) * 8;
    float bv = bias[n0 + n];
    float v[8];
#pragma unroll
    for (int j = 0; j < 8; ++j) v[j] = Cs[n * 72 + c + j] + bv;
    size_t off = ((size_t)t * G_SZ + (n0 + n)) * B_SZ + bbase + c;
    if (x_is_f32) {
      float4* dst = (float4*)((float*)Xout + off);
      dst[0] = make_float4(v[0], v[1], v[2], v[3]);
      dst[1] = make_float4(v[4], v[5], v[6], v[7]);
    } else {
      short8 o;
#pragma unroll
      for (int j = 0; j < 8; ++j) o[j] = (short)f2bf(v[j]);
      *(short8*)((unsigned short*)Xout + off) = o;
    }
  }
}

// ---------------------------------------------------------------------------
// Phase 2: LSTM recurrence, LN folded into GEMM. One barrier/step, per-rb-
// group (96 blocks). Partial stats: plain stores + redundant reduce.
// ---------------------------------------------------------------------------
__device__ __forceinline__ void gridbar(unsigned int* leaf, unsigned int* root,
                                        int idx, int sub) {
  __syncthreads();
  if (threadIdx.x == 0) {
    unsigned int old = __hip_atomic_fetch_add(&leaf[idx * 8 + sub], 1u,
                                              __ATOMIC_ACQ_REL, __HIP_MEMORY_SCOPE_AGENT);
    if (old == 11u)
      __hip_atomic_fetch_add(&root[idx], 1u, __ATOMIC_ACQ_REL, __HIP_MEMORY_SCOPE_AGENT);
    while (__hip_atomic_load(&root[idx], __ATOMIC_ACQUIRE, __HIP_MEMORY_SCOPE_AGENT) < 8u)
      __builtin_amdgcn_s_sleep(1);
  }
  __syncthreads();
}

__global__ __launch_bounds__(128) void lstm_kernel(
    const unsigned short* __restrict__ Whh_hi, const unsigned short* __restrict__ Whh_lo,
    const void* __restrict__ X, int x_is_f32,
    const float* __restrict__ SWp, const float* __restrict__ Sbeta,
    const float* __restrict__ gamma_h, const float* __restrict__ beta_h,
    const float* __restrict__ gamma_c, const float* __restrict__ beta_c,
    const int* __restrict__ lens,
    unsigned short* __restrict__ Hhi, unsigned short* __restrict__ Hlo,
    float* __restrict__ part,
    unsigned int* __restrict__ bar, float* __restrict__ out) {
  __shared__ unsigned short Wt[32 * 776];   // 49664 B
  __shared__ float glds[4][32][8];          // gate pre-activations
  __shared__ float cst[32][8];              // raw c state (pre-LN)
  __shared__ float hpre[32][8];             // raw h state (pre-LN)
  __shared__ float pstat2[32][4][4];        // per-thread partials [row][jjA][s]
  __shared__ float rstat[32][4];            // {rh, muh*rh, rc, muc*rc}
  __shared__ float ghs[8], bhs[8], gcs[8], bcs[8];

  int bidx = blockIdx.x;
  int jb = bidx % 96, rb = bidx / 96;
  int j0 = jb * 8, b0 = rb * 32;
  int tid = threadIdx.x;
  int w = tid >> 6, lane = tid & 63;
  int lrow = lane & 15, lkq = lane >> 4;
  int sub = jb / 12;
  unsigned int* leaf = bar;          // [(t*4+rb)*8 + sub]
  unsigned int* root = bar + 2048;   // [t*4+rb]

  // persistent W' hi slice: LDS row r <-> gate r>>3, jj r&7
  for (int c = tid; c < 3072; c += 128) {
    int row = c / 96, ko = (c - row * 96) * 8;
    short8 v = *(const short8*)(Whh_hi +
        ((size_t)((row >> 3) * H_SZ + j0 + (row & 7))) * H_SZ + ko);
    *(short8*)(&Wt[row * 776 + ko]) = v;
  }
  if (tid < 8) {
    ghs[tid] = gamma_h[j0 + tid]; bhs[tid] = beta_h[j0 + tid];
    gcs[tid] = gamma_c[j0 + tid]; bcs[tid] = beta_c[j0 + tid];
  }
  for (int c = tid; c < 256; c += 128) {
    cst[c >> 3][c & 7] = 0.f;
    hpre[c >> 3][c & 7] = 0.f;
  }

  int myrow = tid & 31;
  int jjA = tid >> 5;               // 0..3, handles jj = 2*jjA, 2*jjA+1
  int jjp = jjA * 2;
  int mylen = lens[b0 + myrow];
  int myWrow = (w << 4) | lrow;     // 0..31: this lane's gate-row (n)
  int gate4 = myWrow >> 3, jjl = myWrow & 7;
  int g_global = gate4 * H_SZ + j0 + jjl;
  float mySW = SWp[g_global];
  float mySb = Sbeta[g_global];
  const unsigned short* wbase = &Wt[(size_t)myWrow * 776];
  const unsigned short* wlo = Whh_lo + (size_t)g_global * H_SZ;
  __syncthreads();

  // ------------------------- t = 0: gates = X(0) -------------------------
  {
    float xv[2][4];
    size_t xbase = ((size_t)0 * G_SZ + g_global) * B_SZ + b0 + lkq * 4;
#pragma unroll
    for (int mt = 0; mt < 2; ++mt) {
      if (x_is_f32) {
        float4 p = *(const float4*)((const float*)X + xbase + mt * 16);
        xv[mt][0] = p.x; xv[mt][1] = p.y; xv[mt][2] = p.z; xv[mt][3] = p.w;
      } else {
        ushort4 p = *(const ushort4*)((const unsigned short*)X + xbase + mt * 16);
        xv[mt][0] = bf2f(p.x); xv[mt][1] = bf2f(p.y);
        xv[mt][2] = bf2f(p.z); xv[mt][3] = bf2f(p.w);
      }
#pragma unroll
      for (int rr = 0; rr < 4; ++rr)
        glds[gate4][mt * 16 + lkq * 4 + rr][jjl] = xv[mt][rr];
    }
  }
  __syncthreads();
  // cell(0): c0 = 0 raw, h0 = 0 (GEMM skipped)
  {
    float ph = 0.f, ph2 = 0.f, pc = 0.f, pc2 = 0.f;
#pragma unroll
    for (int q = 0; q < 2; ++q) {
      int jj = jjp + q;
      float iv = glds[0][myrow][jj], fv = glds[1][myrow][jj];
      float gv = glds[2][myrow][jj], ov = glds[3][myrow][jj];
      float si = 1.f / (1.f + expf(-iv));
      float so = 1.f / (1.f + expf(-ov));
      (void)fv;
      float cn = si * tanhf(gv);          // sf * 0 + ...
      float hp = so * tanhf(cn);
      cst[myrow][jj] = cn;
      hpre[myrow][jj] = hp;
      ph += hp; ph2 += hp * hp; pc += cn; pc2 += cn * cn;
    }
    // h_pre(0) -> parity 0
    size_t hx = (size_t)(b0 + myrow) * H_SZ + j0 + jjp;
    unsigned short h0 = f2bf(hpre[myrow][jjp]);
    unsigned short h1 = f2bf(hpre[myrow][jjp + 1]);
    *(ushort2*)&Hhi[hx] = make_ushort2(h0, h1);
    *(ushort2*)&Hlo[hx] = make_ushort2(
        f2bf(hpre[myrow][jjp] - bf2f(h0)),
        f2bf(hpre[myrow][jjp + 1] - bf2f(h1)));
    pstat2[myrow][jjA][0] = ph; pstat2[myrow][jjA][1] = ph2;
    pstat2[myrow][jjA][2] = pc; pstat2[myrow][jjA][3] = pc2;
  }
  __syncthreads();
  {
    float v = pstat2[tid >> 2][0][tid & 3] + pstat2[tid >> 2][1][tid & 3] +
              pstat2[tid >> 2][2][tid & 3] + pstat2[tid >> 2][3][tid & 3];
    part[((size_t)(0 * 4 + rb) * 128 + tid) * 96 + jb] = v;
  }
  gridbar(leaf, root, 0 * 4 + rb, sub);

  // ------------------------- t = 1 .. 63 -------------------------
  for (int t = 1; t < T_LEN; ++t) {
    int pr = (t - 1) & 1, pw = t & 1;
    // prefetch X(t) early
    float xv[2][4];
    {
      size_t xbase = ((size_t)t * G_SZ + g_global) * B_SZ + b0 + lkq * 4;
#pragma unroll
      for (int mt = 0; mt < 2; ++mt) {
        if (x_is_f32) {
          float4 p = *(const float4*)((const float*)X + xbase + mt * 16);
          xv[mt][0] = p.x; xv[mt][1] = p.y; xv[mt][2] = p.z; xv[mt][3] = p.w;
        } else {
          ushort4 p = *(const ushort4*)((const unsigned short*)X + xbase + mt * 16);
          xv[mt][0] = bf2f(p.x); xv[mt][1] = bf2f(p.y);
          xv[mt][2] = bf2f(p.z); xv[mt][3] = bf2f(p.w);
        }
      }
    }
    // ---- GEMM: acc = h_pre(t-1) . W'^T (3-term hi/lo)
    const unsigned short* h0h = Hhi + (size_t)pr * HPL + (size_t)(b0 + lrow) * H_SZ;
    const unsigned short* h0l = Hlo + (size_t)pr * HPL + (size_t)(b0 + lrow) * H_SZ;
    const unsigned short* h1h = Hhi + (size_t)pr * HPL + (size_t)(b0 + 16 + lrow) * H_SZ;
    const unsigned short* h1l = Hlo + (size_t)pr * HPL + (size_t)(b0 + 16 + lrow) * H_SZ;
    f32x4 acc0 = {}, acc1 = {};
#pragma unroll 4
    for (int kt = 0; kt < 24; ++kt) {
      int k0 = kt * 32 + lkq * 8;
      bf16x8 wh = *(const bf16x8*)(wbase + k0);
      bf16x8 wl = *(const bf16x8*)(wlo + k0);
      bf16x8 a0h = *(const bf16x8*)(h0h + k0);
      bf16x8 a0l = *(const bf16x8*)(h0l + k0);
      bf16x8 a1h = *(const bf16x8*)(h1h + k0);
      bf16x8 a1l = *(const bf16x8*)(h1l + k0);
      acc0 = __builtin_amdgcn_mfma_f32_16x16x32_bf16(a0h, wh, acc0, 0, 0, 0);
      acc1 = __builtin_amdgcn_mfma_f32_16x16x32_bf16(a1h, wh, acc1, 0, 0, 0);
      acc0 = __builtin_amdgcn_mfma_f32_16x16x32_bf16(a0l, wh, acc0, 0, 0, 0);
      acc1 = __builtin_amdgcn_mfma_f32_16x16x32_bf16(a1l, wh, acc1, 0, 0, 0);
      acc0 = __builtin_amdgcn_mfma_f32_16x16x32_bf16(a0h, wl, acc0, 0, 0, 0);
      acc1 = __builtin_amdgcn_mfma_f32_16x16x32_bf16(a1h, wl, acc1, 0, 0, 0);
    }
    // ---- reduce stats(t-1): 96 partials, coalesced
    float psum = 0.f;
    {
      const float4* pb = (const float4*)(part + ((size_t)((t - 1) * 4 + rb) * 128 + tid) * 96);
#pragma unroll
      for (int i = 0; i < 24; ++i) {
        float4 v = pb[i];
        psum += v.x + v.y + v.z + v.w;
      }
    }
    {
      int s = tid & 3;
      float x1 = __shfl_xor(psum, 1);
      float x2 = __shfl_xor(psum, 2);
      float x3 = __shfl_xor(x1, 2);
      float s0 = pick4(s ^ 0, psum, x1, x2, x3);
      float s1 = pick4(s ^ 1, psum, x1, x2, x3);
      float s2 = pick4(s ^ 2, psum, x1, x2, x3);
      float s3 = pick4(s ^ 3, psum, x1, x2, x3);
      float muh = s0 * (1.f / 768.f), muc = s2 * (1.f / 768.f);
      float vh = s1 * (1.f / 768.f) - muh * muh;
      float vc = s3 * (1.f / 768.f) - muc * muc;
      float rh = rsqrtf(vh + LN_EPS), rc = rsqrtf(vc + LN_EPS);
      float fin = (s == 0) ? rh : (s == 1) ? muh * rh : (s == 2) ? rc : muc * rc;
      rstat[tid >> 2][s] = fin;
    }
    __syncthreads();
    // ---- assemble gates(t) = X + rh*acc - (muh*rh)*SW' + Sbeta
#pragma unroll
    for (int mt = 0; mt < 2; ++mt) {
      f32x4 a = mt ? acc1 : acc0;
#pragma unroll
      for (int rr = 0; rr < 4; ++rr) {
        int row = mt * 16 + lkq * 4 + rr;
        float2 rv = *(float2*)&rstat[row][0];
        glds[gate4][row][jjl] = xv[mt][rr] + rv.x * a[rr] - rv.y * mySW + mySb;
      }
    }
    __syncthreads();
    // ---- cell(t) + output write for told = t-1
    {
      float4 rv = *(float4*)&rstat[myrow][0];   // rh, muh*rh, rc, muc*rc
      int told = t - 1;
      if (told == mylen - 1) {
#pragma unroll
        for (int q = 0; q < 2; ++q) {
          int jj = jjp + q;
          out[(size_t)(b0 + myrow) * H_SZ + j0 + jj] =
              (rv.x * hpre[myrow][jj] - rv.y) * ghs[jj] + bhs[jj];
        }
      }
      float ph = 0.f, ph2 = 0.f, pc = 0.f, pc2 = 0.f;
      float hnew[2];
#pragma unroll
      for (int q = 0; q < 2; ++q) {
        int jj = jjp + q;
        float cprev = (rv.z * cst[myrow][jj] - rv.w) * gcs[jj] + bcs[jj];  // LN(c)
        float iv = glds[0][myrow][jj], fv = glds[1][myrow][jj];
        float gv = glds[2][myrow][jj], ov = glds[3][myrow][jj];
        float si = 1.f / (1.f + expf(-iv));
        float sf = 1.f / (1.f + expf(-fv));
        float so = 1.f / (1.f + expf(-ov));
        float cn = sf * cprev + si * tanhf(gv);
        float hp = so * tanhf(cn);
        cst[myrow][jj] = cn;
        hpre[myrow][jj] = hp;
        hnew[q] = hp;
        ph += hp; ph2 += hp * hp; pc += cn; pc2 += cn * cn;
      }
      size_t hx = (size_t)pw * HPL + (size_t)(b0 + myrow) * H_SZ + j0 + jjp;
      unsigned short h0 = f2bf(hnew[0]);
      unsigned short h1 = f2bf(hnew[1]);
      *(ushort2*)&Hhi[hx] = make_ushort2(h0, h1);
      *(ushort2*)&Hlo[hx] = make_ushort2(f2bf(hnew[0] - bf2f(h0)),
                                         f2bf(hnew[1] - bf2f(h1)));
      pstat2[myrow][jjA][0] = ph; pstat2[myrow][jjA][1] = ph2;
      pstat2[myrow][jjA][2] = pc; pstat2[myrow][jjA][3] = pc2;
    }
    __syncthreads();
    {
      float v = pstat2[tid >> 2][0][tid & 3] + pstat2[tid >> 2][1][tid & 3] +
                pstat2[tid >> 2][2][tid & 3] + pstat2[tid >> 2][3][tid & 3];
      part[((size_t)(t * 4 + rb) * 128 + tid) * 96 + jb] = v;
    }
    gridbar(leaf, root, t * 4 + rb, sub);
  }

  // ------------------------- tail: rows with len == 64 -------------------------
  {
    float psum = 0.f;
    const float4* pb = (const float4*)(part + ((size_t)(63 * 4 + rb) * 128 + tid) * 96);
#pragma unroll
    for (int i = 0; i < 24; ++i) {
      float4 v = pb[i];
      psum += v.x + v.y + v.z + v.w;
    }
    int s = tid & 3;
    float x1 = __shfl_xor(psum, 1);
    float x2 = __shfl_xor(psum, 2);
    float x3 = __shfl_xor(x1, 2);
    float s0 = pick4(s ^ 0, psum, x1, x2, x3);
    float s1 = pick4(s ^ 1, psum, x1, x2, x3);
    float muh = s0 * (1.f / 768.f);
    float vh = s1 * (1.f / 768.f) - muh * muh;
    float rh = rsqrtf(vh + LN_EPS);
    float fin = (s == 0) ? rh : muh * rh;
    if (s < 2) rstat[tid >> 2][s] = fin;
  }
  __syncthreads();
  if (mylen == T_LEN) {
    float2 rv = *(float2*)&rstat[myrow][0];
#pragma unroll
    for (int q = 0; q < 2; ++q) {
      int jj = jjp + q;
      out[(size_t)(b0 + myrow) * H_SZ + j0 + jj] =
          (rv.x * hpre[myrow][jj] - rv.y) * ghs[jj] + bhs[jj];
    }
  }
}

// ---------------------------------------------------------------------------
extern "C" void kernel_launch(void* const* d_in, const int* in_sizes, int n_in,
                              void* d_out, int out_size, void* d_ws, size_t ws_size,
                              hipStream_t stream) {
  const int*   msg     = (const int*)d_in[0];
  const int*   lens    = (const int*)d_in[1];
  const float* table   = (const float*)d_in[2];
  const float* W_ih    = (const float*)d_in[3];
  const float* W_hh    = (const float*)d_in[4];
  const float* b_ih    = (const float*)d_in[5];
  const float* b_hh    = (const float*)d_in[6];
  const float* gamma_h = (const float*)d_in[7];
  const float* beta_h  = (const float*)d_in[8];
  const float* gamma_c = (const float*)d_in[9];
  const float* beta_c  = (const float*)d_in[10];
  float* out = (float*)d_out;

  size_t szA = (size_t)8192 * 768 * 2;
  size_t szW = (size_t)3072 * 768 * 2;
  size_t szF = 3072 * 4;
  size_t szH = (size_t)2 * HPL * 2;          // 2 parities
  size_t szBar = 2304 * 4;
  size_t rest = 2 * szA + 4 * szW + 3 * szF + 2 * szH + szBar;
  size_t xf32 = (size_t)64 * 3072 * 128 * 4;
  int x_is_f32 = (ws_size >= xf32 + rest) ? 1 : 0;

  char* p = (char*)d_ws;
  void* X = (void*)p;               p += x_is_f32 ? xf32 : (xf32 / 2);
  unsigned short* A_hi   = (unsigned short*)p; p += szA;
  unsigned short* A_lo   = (unsigned short*)p; p += szA;
  unsigned short* Wih_hi = (unsigned short*)p; p += szW;
  unsigned short* Wih_lo = (unsigned short*)p; p += szW;
  unsigned short* Whh_hi = (unsigned short*)p; p += szW;
  unsigned short* Whh_lo = (unsigned short*)p; p += szW;
  float* SWp   = (float*)p;         p += szF;
  float* Sbeta = (float*)p;         p += szF;
  float* bias  = (float*)p;         p += szF;
  unsigned short* Hhi = (unsigned short*)p; p += szH;
  unsigned short* Hlo = (unsigned short*)p; p += szH;
  unsigned int* bar = (unsigned int*)p;     p += szBar;
  // part overlays the A buffers (xproj finished before lstm starts):
  float* part = (float*)A_hi;   // needs 12.6 MB < 25.2 MB of A_hi+A_lo

  hipLaunchKernelGGL(prep_kernel, dim3(1024), dim3(256), 0, stream,
                     msg, table, W_ih, W_hh, b_ih, b_hh, gamma_h, beta_h,
                     A_hi, A_lo, Wih_hi, Wih_lo, Whh_hi, Whh_lo,
                     SWp, Sbeta, bias, Hhi, Hlo, bar);
  hipLaunchKernelGGL(xproj_kernel, dim3(6144), dim3(256), 0, stream,
                     A_hi, A_lo, Wih_hi, Wih_lo, bias, X, x_is_f32);

  void* kargs[] = { (void*)&Whh_hi, (void*)&Whh_lo, (void*)&X, (void*)&x_is_f32,
                    (void*)&SWp, (void*)&Sbeta,
                    (void*)&gamma_h, (void*)&beta_h, (void*)&gamma_c, (void*)&beta_c,
                    (void*)&lens, (void*)&Hhi, (void*)&Hlo, (void*)&part,
                    (void*)&bar, (void*)&out };
  hipLaunchCooperativeKernel((void*)lstm_kernel, dim3(384), dim3(128), kargs, 0, stream);
}

// Round 4
// 2355.292 us; speedup vs baseline: 2.1337x; 1.6490x over previous
//
#include <hip/hip_runtime.h>
#include <stdint.h>

#define T_LEN 64
#define B_SZ  128
#define H_SZ  768
#define G_SZ  3072
#define E_SZ  768
#define LN_EPS 1e-5f

typedef __bf16 bf16x8 __attribute__((ext_vector_type(8)));
typedef float  f32x4  __attribute__((ext_vector_type(4)));
typedef short  short8 __attribute__((ext_vector_type(8)));

__device__ __forceinline__ float bf2f(unsigned short h) {
  unsigned int u = ((unsigned int)h) << 16;
  return __builtin_bit_cast(float, u);
}
__device__ __forceinline__ unsigned short f2bf(float f) {
  unsigned int u = __builtin_bit_cast(unsigned int, f);
  u += 0x7fffu + ((u >> 16) & 1u);   // RNE
  return (unsigned short)(u >> 16);
}
__device__ __forceinline__ void split8(float4 v0, float4 v1, short8& hi, short8& lo) {
  float v[8] = {v0.x, v0.y, v0.z, v0.w, v1.x, v1.y, v1.z, v1.w};
#pragma unroll
  for (int j = 0; j < 8; ++j) {
    unsigned short h = f2bf(v[j]);
    hi[j] = (short)h;
    lo[j] = (short)f2bf(v[j] - bf2f(h));
  }
}

// ---------------------------------------------------------------------------
// Prep
// ---------------------------------------------------------------------------
__global__ void prep_kernel(const int* __restrict__ msg,
                            const float* __restrict__ table,
                            const float* __restrict__ W_ih,
                            const float* __restrict__ W_hh,
                            const float* __restrict__ b_ih,
                            const float* __restrict__ b_hh,
                            const float* __restrict__ gamma_h,
                            const float* __restrict__ beta_h,
                            unsigned short* __restrict__ A_hi,
                            unsigned short* __restrict__ A_lo,
                            unsigned short* __restrict__ Wih_hi,
                            unsigned short* __restrict__ Wih_lo,
                            unsigned short* __restrict__ Whh_hi,
                            unsigned short* __restrict__ Whh_lo,
                            float* __restrict__ SWp,
                            float* __restrict__ Sbeta,
                            float* __restrict__ bias,
                            unsigned int* __restrict__ bar) {
  int idx = blockIdx.x * blockDim.x + threadIdx.x;
  int stride = gridDim.x * blockDim.x;
  // Embedding gather, n = t*128+b
  for (int c = idx; c < 8192 * 96; c += stride) {
    int n = c / 96;
    int ko = (c - n * 96) * 8;
    int b = n & 127, t = n >> 7;
    int m = msg[b * T_LEN + t];
    const float4* s4 = (const float4*)(table + (size_t)m * E_SZ + ko);
    short8 hi, lo;
    split8(s4[0], s4[1], hi, lo);
    *(short8*)(A_hi + (size_t)n * E_SZ + ko) = hi;
    *(short8*)(A_lo + (size_t)n * E_SZ + ko) = lo;
  }
  // Layer-1 weight splits. Whh scaled by gamma_h[j].
  for (int c = idx; c < G_SZ * E_SZ / 8; c += stride) {
    int o8 = c * 8;
    {
      const float4* s4 = (const float4*)(W_ih + (size_t)G_SZ * E_SZ + o8);
      short8 hi, lo;
      split8(s4[0], s4[1], hi, lo);
      *(short8*)(Wih_hi + o8) = hi;
      *(short8*)(Wih_lo + o8) = lo;
    }
    {
      int g = o8 / H_SZ;
      int j = o8 - g * H_SZ;
      const float4* s4 = (const float4*)(W_hh + (size_t)G_SZ * H_SZ + o8);
      const float4* g4 = (const float4*)(gamma_h + j);
      float4 v0 = s4[0], v1 = s4[1];
      float4 w0 = g4[0], w1 = g4[1];
      v0.x *= w0.x; v0.y *= w0.y; v0.z *= w0.z; v0.w *= w0.w;
      v1.x *= w1.x; v1.y *= w1.y; v1.z *= w1.z; v1.w *= w1.w;
      short8 hi, lo;
      split8(v0, v1, hi, lo);
      *(short8*)(Whh_hi + o8) = hi;
      *(short8*)(Whh_lo + o8) = lo;
    }
  }
  for (int g = idx; g < G_SZ; g += stride) {
    const float4* wr = (const float4*)(W_hh + (size_t)G_SZ * H_SZ + (size_t)g * H_SZ);
    const float4* gm = (const float4*)gamma_h;
    const float4* bt = (const float4*)beta_h;
    float sw = 0.f, sb = 0.f;
    for (int i = 0; i < H_SZ / 4; ++i) {
      float4 wv = wr[i], gv = gm[i], bv = bt[i];
      sw += wv.x * gv.x + wv.y * gv.y + wv.z * gv.z + wv.w * gv.w;
      sb += wv.x * bv.x + wv.y * bv.y + wv.z * bv.z + wv.w * bv.w;
    }
    SWp[g] = sw;
    Sbeta[g] = sb;
    bias[g] = b_ih[G_SZ + g] + b_hh[G_SZ + g];
  }
  for (int c = idx; c < 18432; c += stride) bar[c] = 0u;
}

// ---------------------------------------------------------------------------
// Phase 1: X[t][g][b] = A . Wih^T + bias (3-term double-bf16 MFMA)
// ---------------------------------------------------------------------------
#define K2_STR 56

__global__ __launch_bounds__(256) void xproj_kernel(
    const unsigned short* __restrict__ A_hi, const unsigned short* __restrict__ A_lo,
    const unsigned short* __restrict__ B_hi, const unsigned short* __restrict__ B_lo,
    const float* __restrict__ bias, void* __restrict__ Xout, int x_is_f32) {
  __shared__ float smemf[7168];
  unsigned short* AsH = (unsigned short*)smemf;
  unsigned short* AsL = AsH + 64 * K2_STR;
  unsigned short* BsH = AsL + 64 * K2_STR;
  unsigned short* BsL = BsH + 64 * K2_STR;

  int bid = blockIdx.x;
  int mchunk = bid / 384;
  int r = bid - mchunk * 384;
  int nb = r >> 3;
  int mb = (mchunk << 3) + (r & 7);
  int m0 = mb * 64, n0 = nb * 64;
  int tid = threadIdx.x;
  int w = tid >> 6, lane = tid & 63;
  int wm = w & 1, wn = w >> 1;
  int rs = tid >> 2, ks = (tid & 3) * 8;
  int lrow = lane & 15, lk = (lane >> 4) * 8;

  f32x4 acc[2][2] = {};
  const unsigned short* gA = A_hi + (size_t)(m0 + rs) * E_SZ + ks;
  const unsigned short* gAl = A_lo + (size_t)(m0 + rs) * E_SZ + ks;
  const unsigned short* gB = B_hi + (size_t)(n0 + rs) * E_SZ + ks;
  const unsigned short* gBl = B_lo + (size_t)(n0 + rs) * E_SZ + ks;
  short8 vah = *(const short8*)gA;
  short8 val = *(const short8*)gAl;
  short8 vbh = *(const short8*)gB;
  short8 vbl = *(const short8*)gBl;
  for (int kt = 0; kt < 24; ++kt) {
    __syncthreads();
    *(short8*)(AsH + rs * K2_STR + ks) = vah;
    *(short8*)(AsL + rs * K2_STR + ks) = val;
    *(short8*)(BsH + rs * K2_STR + ks) = vbh;
    *(short8*)(BsL + rs * K2_STR + ks) = vbl;
    __syncthreads();
    if (kt < 23) {
      int k0 = (kt + 1) * 32;
      vah = *(const short8*)(gA + k0);
      val = *(const short8*)(gAl + k0);
      vbh = *(const short8*)(gB + k0);
      vbl = *(const short8*)(gBl + k0);
    }
    bf16x8 ah0 = *(const bf16x8*)(AsH + (wm * 32 +      lrow) * K2_STR + lk);
    bf16x8 ah1 = *(const bf16x8*)(AsH + (wm * 32 + 16 + lrow) * K2_STR + lk);
    bf16x8 al0 = *(const bf16x8*)(AsL + (wm * 32 +      lrow) * K2_STR + lk);
    bf16x8 al1 = *(const bf16x8*)(AsL + (wm * 32 + 16 + lrow) * K2_STR + lk);
    bf16x8 bh0 = *(const bf16x8*)(BsH + (wn * 32 +      lrow) * K2_STR + lk);
    bf16x8 bh1 = *(const bf16x8*)(BsH + (wn * 32 + 16 + lrow) * K2_STR + lk);
    bf16x8 bl0 = *(const bf16x8*)(BsL + (wn * 32 +      lrow) * K2_STR + lk);
    bf16x8 bl1 = *(const bf16x8*)(BsL + (wn * 32 + 16 + lrow) * K2_STR + lk);
    acc[0][0] = __builtin_amdgcn_mfma_f32_16x16x32_bf16(ah0, bh0, acc[0][0], 0, 0, 0);
    acc[1][0] = __builtin_amdgcn_mfma_f32_16x16x32_bf16(ah1, bh0, acc[1][0], 0, 0, 0);
    acc[0][1] = __builtin_amdgcn_mfma_f32_16x16x32_bf16(ah0, bh1, acc[0][1], 0, 0, 0);
    acc[1][1] = __builtin_amdgcn_mfma_f32_16x16x32_bf16(ah1, bh1, acc[1][1], 0, 0, 0);
    acc[0][0] = __builtin_amdgcn_mfma_f32_16x16x32_bf16(al0, bh0, acc[0][0], 0, 0, 0);
    acc[1][0] = __builtin_amdgcn_mfma_f32_16x16x32_bf16(al1, bh0, acc[1][0], 0, 0, 0);
    acc[0][1] = __builtin_amdgcn_mfma_f32_16x16x32_bf16(al0, bh1, acc[0][1], 0, 0, 0);
    acc[1][1] = __builtin_amdgcn_mfma_f32_16x16x32_bf16(al1, bh1, acc[1][1], 0, 0, 0);
    acc[0][0] = __builtin_amdgcn_mfma_f32_16x16x32_bf16(ah0, bl0, acc[0][0], 0, 0, 0);
    acc[1][0] = __builtin_amdgcn_mfma_f32_16x16x32_bf16(ah1, bl0, acc[1][0], 0, 0, 0);
    acc[0][1] = __builtin_amdgcn_mfma_f32_16x16x32_bf16(ah0, bl1, acc[0][1], 0, 0, 0);
    acc[1][1] = __builtin_amdgcn_mfma_f32_16x16x32_bf16(ah1, bl1, acc[1][1], 0, 0, 0);
  }
  __syncthreads();
  float* Cs = smemf;
  int quad = lane >> 4;
#pragma unroll
  for (int mt = 0; mt < 2; ++mt)
#pragma unroll
    for (int nt = 0; nt < 2; ++nt) {
      int mloc = wm * 32 + mt * 16 + quad * 4;
      int nloc = wn * 32 + nt * 16 + lrow;
#pragma unroll
      for (int rr = 0; rr < 4; ++rr) Cs[nloc * 72 + mloc + rr] = acc[mt][nt][rr];
    }
  __syncthreads();
  int t = mb >> 1, bbase = (mb & 1) * 64;
#pragma unroll
  for (int rep = 0; rep < 2; ++rep) {
    int n = (tid >> 3) + rep * 32;
    int c = (tid & 7) * 8;
    float bv = bias[n0 + n];
    float v[8];
#pragma unroll
    for (int j = 0; j < 8; ++j) v[j] = Cs[n * 72 + c + j] + bv;
    size_t off = ((size_t)t * G_SZ + (n0 + n)) * B_SZ + bbase + c;
    if (x_is_f32) {
      float4* dst = (float4*)((float*)Xout + off);
      dst[0] = make_float4(v[0], v[1], v[2], v[3]);
      dst[1] = make_float4(v[4], v[5], v[6], v[7]);
    } else {
      short8 o;
#pragma unroll
      for (int j = 0; j < 8; ++j) o[j] = (short)f2bf(v[j]);
      *(short8*)((unsigned short*)Xout + off) = o;
    }
  }
}

// ---------------------------------------------------------------------------
// Phase 2: LSTM recurrence. 192 blocks = 96 jb x 2 rb (64 b-rows each).
// Relaxed-atomic grid barrier with single release/acquire fences.
// H-state: padded 64B chunks Hbuf[parity][b][jb][32] (hi 8 + lo 8 + pad).
// ---------------------------------------------------------------------------
__device__ __forceinline__ void gridbar(unsigned int* leaf, unsigned int* root,
                                        int idx, int sub) {
  __syncthreads();
  if (threadIdx.x == 0) {
    __builtin_amdgcn_fence(__ATOMIC_RELEASE, "agent");
    unsigned int old = __hip_atomic_fetch_add(&leaf[idx * 128 + sub * 16], 1u,
                                              __ATOMIC_RELAXED, __HIP_MEMORY_SCOPE_AGENT);
    if (old == 11u)
      __hip_atomic_fetch_add(&root[idx * 16], 1u,
                             __ATOMIC_RELAXED, __HIP_MEMORY_SCOPE_AGENT);
    while (__hip_atomic_load(&root[idx * 16], __ATOMIC_RELAXED,
                             __HIP_MEMORY_SCOPE_AGENT) < 8u)
      __builtin_amdgcn_s_sleep(2);
    __builtin_amdgcn_fence(__ATOMIC_ACQUIRE, "agent");
  }
  __syncthreads();
}

__global__ __launch_bounds__(128) void lstm_kernel(
    const unsigned short* __restrict__ Whh_lo,
    const unsigned short* __restrict__ Whh_hi,
    const void* __restrict__ X, int x_is_f32,
    const float* __restrict__ SWp, const float* __restrict__ Sbeta,
    const float* __restrict__ gamma_h, const float* __restrict__ beta_h,
    const float* __restrict__ gamma_c, const float* __restrict__ beta_c,
    const int* __restrict__ lens,
    unsigned short* __restrict__ Hbuf, float* __restrict__ part,
    unsigned int* __restrict__ bar, float* __restrict__ out) {
  __shared__ unsigned short Wt[32 * 776];   // 49664 B
  __shared__ float glds[4 * 8 * 72];        // gates [gate][jj][row(64), stride 72]
  __shared__ float pstat2[128 * 4];         // [row*2+half][s]
  __shared__ float rstat4[256];             // raw sums [row][s]
  __shared__ float rstat[256];              // {rh, muh*rh, rc, muc*rc} per row
  __shared__ float ghs[8], bhs[8], gcs[8], bcs[8];

  int bidx = blockIdx.x;
  int jb = bidx % 96, rb = bidx / 96;
  int j0 = jb * 8, b0 = rb * 64;
  int tid = threadIdx.x;
  int w = tid >> 6, lane = tid & 63;
  int lrow = lane & 15, lkq = lane >> 4;
  int sub = jb / 12;
  unsigned int* leaf = bar;           // [idx*128 + sub*16]
  unsigned int* root = bar + 16384;   // [idx*16]

  // persistent W'_hi slice in LDS: row r <-> gate r>>3, jj r&7
  for (int c = tid; c < 3072; c += 128) {
    int row = c / 96, ko = (c - row * 96) * 8;
    short8 v = *(const short8*)(Whh_hi +
        ((size_t)((row >> 3) * H_SZ + j0 + (row & 7))) * H_SZ + ko);
    *(short8*)(&Wt[row * 776 + ko]) = v;
  }
  if (tid < 8) {
    ghs[tid] = gamma_h[j0 + tid]; bhs[tid] = beta_h[j0 + tid];
    gcs[tid] = gamma_c[j0 + tid]; bcs[tid] = beta_c[j0 + tid];
  }

  int row = tid & 63;               // cell row
  int half = tid >> 6;              // 0/1
  int jjq = half * 4;               // jj quad base
  int mylen = lens[b0 + row];
  int myWrow = (w << 4) | lrow;     // 0..31 gate-row
  int gate4 = myWrow >> 3, jjl = myWrow & 7;
  int g_global = gate4 * H_SZ + j0 + jjl;
  float mySW = SWp[g_global];
  float mySb = Sbeta[g_global];
  const unsigned short* wbase = &Wt[(size_t)myWrow * 776];
  const unsigned short* wlo = Whh_lo + (size_t)g_global * H_SZ;
  float c4[4], h4[4];
  __syncthreads();

  // ---------------- t = 0: gates = X(0), c0 = h0 = 0 ----------------
  {
    size_t xbase = ((size_t)0 * G_SZ + g_global) * B_SZ + b0 + lkq * 4;
#pragma unroll
    for (int mt = 0; mt < 4; ++mt) {
      float xr[4];
      if (x_is_f32) {
        float4 p = *(const float4*)((const float*)X + xbase + mt * 16);
        xr[0] = p.x; xr[1] = p.y; xr[2] = p.z; xr[3] = p.w;
      } else {
        ushort4 p = *(const ushort4*)((const unsigned short*)X + xbase + mt * 16);
        xr[0] = bf2f(p.x); xr[1] = bf2f(p.y); xr[2] = bf2f(p.z); xr[3] = bf2f(p.w);
      }
#pragma unroll
      for (int rr = 0; rr < 4; ++rr)
        glds[(gate4 * 8 + jjl) * 72 + mt * 16 + lkq * 4 + rr] = xr[rr];
    }
  }
  __syncthreads();
  {
    float ph = 0.f, ph2 = 0.f, pc = 0.f, pc2 = 0.f;
#pragma unroll
    for (int q = 0; q < 4; ++q) {
      int jj = jjq + q;
      float iv = glds[(0 * 8 + jj) * 72 + row];
      float gv = glds[(2 * 8 + jj) * 72 + row];
      float ov = glds[(3 * 8 + jj) * 72 + row];
      float si = 1.f / (1.f + expf(-iv));
      float so = 1.f / (1.f + expf(-ov));
      float cn = si * tanhf(gv);
      float hp = so * tanhf(cn);
      c4[q] = cn; h4[q] = hp;
      ph += hp; ph2 += hp * hp; pc += cn; pc2 += cn * cn;
    }
    size_t hx = (((size_t)0 * 128 + b0 + row) * 96 + jb) * 32 + jjq;
    ushort4 hiv, lov;
    hiv.x = f2bf(h4[0]); hiv.y = f2bf(h4[1]); hiv.z = f2bf(h4[2]); hiv.w = f2bf(h4[3]);
    lov.x = f2bf(h4[0] - bf2f(hiv.x)); lov.y = f2bf(h4[1] - bf2f(hiv.y));
    lov.z = f2bf(h4[2] - bf2f(hiv.z)); lov.w = f2bf(h4[3] - bf2f(hiv.w));
    *(ushort4*)&Hbuf[hx] = hiv;
    *(ushort4*)&Hbuf[hx + 8] = lov;
    *(f32x4*)&pstat2[(row * 2 + half) * 4] = f32x4{ph, ph2, pc, pc2};
  }
  __syncthreads();
  {
    int f = tid * 2;
    float2 v;
    v.x = pstat2[(f >> 2) * 8 + (f & 3)] + pstat2[(f >> 2) * 8 + 4 + (f & 3)];
    v.y = pstat2[((f + 1) >> 2) * 8 + ((f + 1) & 3)] +
          pstat2[((f + 1) >> 2) * 8 + 4 + ((f + 1) & 3)];
    *(float2*)&part[((size_t)(0 * 2 + rb) * 96 + jb) * 256 + f] = v;
  }
  gridbar(leaf, root, 0 * 2 + rb, sub);

  // ---------------- t = 1 .. 63 ----------------
  for (int t = 1; t < T_LEN; ++t) {
    int pr = (t - 1) & 1, pw = t & 1;
    // X(t) prefetch
    float xv[4][4];
    {
      size_t xbase = ((size_t)t * G_SZ + g_global) * B_SZ + b0 + lkq * 4;
#pragma unroll
      for (int mt = 0; mt < 4; ++mt) {
        if (x_is_f32) {
          float4 p = *(const float4*)((const float*)X + xbase + mt * 16);
          xv[mt][0] = p.x; xv[mt][1] = p.y; xv[mt][2] = p.z; xv[mt][3] = p.w;
        } else {
          ushort4 p = *(const ushort4*)((const unsigned short*)X + xbase + mt * 16);
          xv[mt][0] = bf2f(p.x); xv[mt][1] = bf2f(p.y);
          xv[mt][2] = bf2f(p.z); xv[mt][3] = bf2f(p.w);
        }
      }
    }
    // GEMM: acc = h_pre(t-1) . W'^T (3-term hi/lo)
    f32x4 acc[4] = {};
    {
      const unsigned short* hb[4];
#pragma unroll
      for (int mt = 0; mt < 4; ++mt)
        hb[mt] = Hbuf + ((size_t)pr * 128 + b0 + mt * 16 + lrow) * 3072;
#pragma unroll 4
      for (int kt = 0; kt < 24; ++kt) {
        int k0 = kt * 32 + lkq * 8;
        int co = (kt * 4 + lkq) * 32;
        bf16x8 wh = *(const bf16x8*)(wbase + k0);
        bf16x8 wl = *(const bf16x8*)(wlo + k0);
#pragma unroll
        for (int mt = 0; mt < 4; ++mt) {
          bf16x8 ah = *(const bf16x8*)(hb[mt] + co);
          bf16x8 al = *(const bf16x8*)(hb[mt] + co + 8);
          acc[mt] = __builtin_amdgcn_mfma_f32_16x16x32_bf16(ah, wh, acc[mt], 0, 0, 0);
          acc[mt] = __builtin_amdgcn_mfma_f32_16x16x32_bf16(al, wh, acc[mt], 0, 0, 0);
          acc[mt] = __builtin_amdgcn_mfma_f32_16x16x32_bf16(ah, wl, acc[mt], 0, 0, 0);
        }
      }
    }
    // reduce stats(t-1)
    float psum0 = 0.f, psum1 = 0.f;
    {
      const float* pb = part + ((size_t)((t - 1) * 2 + rb) * 96) * 256 + tid * 2;
#pragma unroll 8
      for (int j = 0; j < 96; ++j) {
        float2 v = *(const float2*)(pb + j * 256);
        psum0 += v.x; psum1 += v.y;
      }
    }
    {
      int f = tid * 2;
      rstat4[f] = psum0;
      rstat4[f + 1] = psum1;
    }
    __syncthreads();
    if (tid < 64) {
      f32x4 s = *(f32x4*)&rstat4[tid * 4];
      float muh = s[0] * (1.f / 768.f), muc = s[2] * (1.f / 768.f);
      float vh = s[1] * (1.f / 768.f) - muh * muh;
      float vc = s[3] * (1.f / 768.f) - muc * muc;
      float rh = rsqrtf(vh + LN_EPS), rc = rsqrtf(vc + LN_EPS);
      *(f32x4*)&rstat[tid * 4] = f32x4{rh, muh * rh, rc, muc * rc};
    }
    __syncthreads();
    // out write for told = t-1 (uses old h4 + rstat(t-1))
    {
      int told = t - 1;
      if (told == mylen - 1) {
        float2 rv = *(float2*)&rstat[row * 4];
#pragma unroll
        for (int q = 0; q < 4; ++q)
          out[(size_t)(b0 + row) * H_SZ + j0 + jjq + q] =
              (rv.x * h4[q] - rv.y) * ghs[jjq + q] + bhs[jjq + q];
      }
    }
    __syncthreads();
    // gates(t) = X + rh*acc - (muh*rh)*SW' + Sbeta
#pragma unroll
    for (int mt = 0; mt < 4; ++mt) {
#pragma unroll
      for (int rr = 0; rr < 4; ++rr) {
        int r2 = mt * 16 + lkq * 4 + rr;
        float2 rv = *(float2*)&rstat[r2 * 4];
        glds[(gate4 * 8 + jjl) * 72 + r2] =
            xv[mt][rr] + rv.x * acc[mt][rr] - rv.y * mySW + mySb;
      }
    }
    __syncthreads();
    // cell(t)
    {
      f32x4 rv = *(f32x4*)&rstat[row * 4];
      float ph = 0.f, ph2 = 0.f, pc = 0.f, pc2 = 0.f;
#pragma unroll
      for (int q = 0; q < 4; ++q) {
        int jj = jjq + q;
        float cprev = (rv[2] * c4[q] - rv[3]) * gcs[jj] + bcs[jj];   // LN(c(t-1))
        float iv = glds[(0 * 8 + jj) * 72 + row];
        float fv = glds[(1 * 8 + jj) * 72 + row];
        float gv = glds[(2 * 8 + jj) * 72 + row];
        float ov = glds[(3 * 8 + jj) * 72 + row];
        float si = 1.f / (1.f + expf(-iv));
        float sf = 1.f / (1.f + expf(-fv));
        float so = 1.f / (1.f + expf(-ov));
        float cn = sf * cprev + si * tanhf(gv);
        float hp = so * tanhf(cn);
        c4[q] = cn; h4[q] = hp;
        ph += hp; ph2 += hp * hp; pc += cn; pc2 += cn * cn;
      }
      size_t hx = (((size_t)pw * 128 + b0 + row) * 96 + jb) * 32 + jjq;
      ushort4 hiv, lov;
      hiv.x = f2bf(h4[0]); hiv.y = f2bf(h4[1]); hiv.z = f2bf(h4[2]); hiv.w = f2bf(h4[3]);
      lov.x = f2bf(h4[0] - bf2f(hiv.x)); lov.y = f2bf(h4[1] - bf2f(hiv.y));
      lov.z = f2bf(h4[2] - bf2f(hiv.z)); lov.w = f2bf(h4[3] - bf2f(hiv.w));
      *(ushort4*)&Hbuf[hx] = hiv;
      *(ushort4*)&Hbuf[hx + 8] = lov;
      *(f32x4*)&pstat2[(row * 2 + half) * 4] = f32x4{ph, ph2, pc, pc2};
    }
    __syncthreads();
    {
      int f = tid * 2;
      float2 v;
      v.x = pstat2[(f >> 2) * 8 + (f & 3)] + pstat2[(f >> 2) * 8 + 4 + (f & 3)];
      v.y = pstat2[((f + 1) >> 2) * 8 + ((f + 1) & 3)] +
            pstat2[((f + 1) >> 2) * 8 + 4 + ((f + 1) & 3)];
      *(float2*)&part[((size_t)(t * 2 + rb) * 96 + jb) * 256 + f] = v;
    }
    gridbar(leaf, root, t * 2 + rb, sub);
  }

  // ---------------- tail: rows with len == 64 ----------------
  {
    float psum0 = 0.f, psum1 = 0.f;
    const float* pb = part + ((size_t)(63 * 2 + rb) * 96) * 256 + tid * 2;
#pragma unroll 8
    for (int j = 0; j < 96; ++j) {
      float2 v = *(const float2*)(pb + j * 256);
      psum0 += v.x; psum1 += v.y;
    }
    rstat4[tid * 2] = psum0;
    rstat4[tid * 2 + 1] = psum1;
  }
  __syncthreads();
  if (tid < 64) {
    f32x4 s = *(f32x4*)&rstat4[tid * 4];
    float muh = s[0] * (1.f / 768.f);
    float vh = s[1] * (1.f / 768.f) - muh * muh;
    float rh = rsqrtf(vh + LN_EPS);
    rstat[tid * 4] = rh;
    rstat[tid * 4 + 1] = muh * rh;
  }
  __syncthreads();
  if (mylen == T_LEN) {
    float2 rv = *(float2*)&rstat[row * 4];
#pragma unroll
    for (int q = 0; q < 4; ++q)
      out[(size_t)(b0 + row) * H_SZ + j0 + jjq + q] =
          (rv.x * h4[q] - rv.y) * ghs[jjq + q] + bhs[jjq + q];
  }
}

// ---------------------------------------------------------------------------
extern "C" void kernel_launch(void* const* d_in, const int* in_sizes, int n_in,
                              void* d_out, int out_size, void* d_ws, size_t ws_size,
                              hipStream_t stream) {
  const int*   msg     = (const int*)d_in[0];
  const int*   lens    = (const int*)d_in[1];
  const float* table   = (const float*)d_in[2];
  const float* W_ih    = (const float*)d_in[3];
  const float* W_hh    = (const float*)d_in[4];
  const float* b_ih    = (const float*)d_in[5];
  const float* b_hh    = (const float*)d_in[6];
  const float* gamma_h = (const float*)d_in[7];
  const float* beta_h  = (const float*)d_in[8];
  const float* gamma_c = (const float*)d_in[9];
  const float* beta_c  = (const float*)d_in[10];
  float* out = (float*)d_out;

  size_t szA = (size_t)8192 * 768 * 2;
  size_t szW = (size_t)3072 * 768 * 2;
  size_t szF = 3072 * 4;
  size_t szH = (size_t)2 * 128 * 96 * 32 * 2;   // Hbuf: 1.5 MB
  size_t szBar = 18432 * 4;
  size_t rest = 2 * szA + 4 * szW + 3 * szF + szH + szBar;
  size_t xf32 = (size_t)64 * 3072 * 128 * 4;
  int x_is_f32 = (ws_size >= xf32 + rest) ? 1 : 0;

  char* p = (char*)d_ws;
  void* X = (void*)p;               p += x_is_f32 ? xf32 : (xf32 / 2);
  unsigned short* A_hi   = (unsigned short*)p; p += szA;
  unsigned short* A_lo   = (unsigned short*)p; p += szA;
  unsigned short* Wih_hi = (unsigned short*)p; p += szW;
  unsigned short* Wih_lo = (unsigned short*)p; p += szW;
  unsigned short* Whh_hi = (unsigned short*)p; p += szW;
  unsigned short* Whh_lo = (unsigned short*)p; p += szW;
  float* SWp   = (float*)p;         p += szF;
  float* Sbeta = (float*)p;         p += szF;
  float* bias  = (float*)p;         p += szF;
  unsigned short* Hbuf = (unsigned short*)p; p += szH;
  unsigned int* bar = (unsigned int*)p;      p += szBar;
  // part overlays A (xproj done before lstm): 128 slots x 96 x 256 x 4B = 12.6 MB
  float* part = (float*)A_hi;

  hipLaunchKernelGGL(prep_kernel, dim3(1024), dim3(256), 0, stream,
                     msg, table, W_ih, W_hh, b_ih, b_hh, gamma_h, beta_h,
                     A_hi, A_lo, Wih_hi, Wih_lo, Whh_hi, Whh_lo,
                     SWp, Sbeta, bias, bar);
  hipLaunchKernelGGL(xproj_kernel, dim3(6144), dim3(256), 0, stream,
                     A_hi, A_lo, Wih_hi, Wih_lo, bias, X, x_is_f32);

  void* kargs[] = { (void*)&Whh_lo, (void*)&Whh_hi, (void*)&X, (void*)&x_is_f32,
                    (void*)&SWp, (void*)&Sbeta,
                    (void*)&gamma_h, (void*)&beta_h, (void*)&gamma_c, (void*)&beta_c,
                    (void*)&lens, (void*)&Hbuf, (void*)&part,
                    (void*)&bar, (void*)&out };
  hipLaunchCooperativeKernel((void*)lstm_kernel, dim3(192), dim3(128), kargs, 0, stream);
}

// Round 5
// 2146.573 us; speedup vs baseline: 2.3411x; 1.0972x over previous
//
#include <hip/hip_runtime.h>
#include <stdint.h>

#define T_LEN 64
#define B_SZ  128
#define H_SZ  768
#define G_SZ  3072
#define E_SZ  768
#define LN_EPS 1e-5f

typedef __bf16 bf16x8 __attribute__((ext_vector_type(8)));
typedef float  f32x4  __attribute__((ext_vector_type(4)));
typedef short  short8 __attribute__((ext_vector_type(8)));

__device__ __forceinline__ float bf2f(unsigned short h) {
  unsigned int u = ((unsigned int)h) << 16;
  return __builtin_bit_cast(float, u);
}
__device__ __forceinline__ unsigned short f2bf(float f) {
  unsigned int u = __builtin_bit_cast(unsigned int, f);
  u += 0x7fffu + ((u >> 16) & 1u);   // RNE
  return (unsigned short)(u >> 16);
}
__device__ __forceinline__ void split8(float4 v0, float4 v1, short8& hi, short8& lo) {
  float v[8] = {v0.x, v0.y, v0.z, v0.w, v1.x, v1.y, v1.z, v1.w};
#pragma unroll
  for (int j = 0; j < 8; ++j) {
    unsigned short h = f2bf(v[j]);
    hi[j] = (short)h;
    lo[j] = (short)f2bf(v[j] - bf2f(h));
  }
}

// ---------------------------------------------------------------------------
// Prep
// ---------------------------------------------------------------------------
__global__ void prep_kernel(const int* __restrict__ msg,
                            const float* __restrict__ table,
                            const float* __restrict__ W_ih,
                            const float* __restrict__ W_hh,
                            const float* __restrict__ b_ih,
                            const float* __restrict__ b_hh,
                            const float* __restrict__ gamma_h,
                            const float* __restrict__ beta_h,
                            unsigned short* __restrict__ A_hi,
                            unsigned short* __restrict__ A_lo,
                            unsigned short* __restrict__ Wih_hi,
                            unsigned short* __restrict__ Wih_lo,
                            unsigned short* __restrict__ Whh_hi,
                            unsigned short* __restrict__ Whh_lo,
                            float* __restrict__ SWp,
                            float* __restrict__ Sbeta,
                            float* __restrict__ bias,
                            unsigned int* __restrict__ bar) {
  int idx = blockIdx.x * blockDim.x + threadIdx.x;
  int stride = gridDim.x * blockDim.x;
  // Embedding gather, n = t*128+b
  for (int c = idx; c < 8192 * 96; c += stride) {
    int n = c / 96;
    int ko = (c - n * 96) * 8;
    int b = n & 127, t = n >> 7;
    int m = msg[b * T_LEN + t];
    const float4* s4 = (const float4*)(table + (size_t)m * E_SZ + ko);
    short8 hi, lo;
    split8(s4[0], s4[1], hi, lo);
    *(short8*)(A_hi + (size_t)n * E_SZ + ko) = hi;
    *(short8*)(A_lo + (size_t)n * E_SZ + ko) = lo;
  }
  // Layer-1 weight splits. Whh scaled by gamma_h[j].
  for (int c = idx; c < G_SZ * E_SZ / 8; c += stride) {
    int o8 = c * 8;
    {
      const float4* s4 = (const float4*)(W_ih + (size_t)G_SZ * E_SZ + o8);
      short8 hi, lo;
      split8(s4[0], s4[1], hi, lo);
      *(short8*)(Wih_hi + o8) = hi;
      *(short8*)(Wih_lo + o8) = lo;
    }
    {
      int g = o8 / H_SZ;
      int j = o8 - g * H_SZ;
      const float4* s4 = (const float4*)(W_hh + (size_t)G_SZ * H_SZ + o8);
      const float4* g4 = (const float4*)(gamma_h + j);
      float4 v0 = s4[0], v1 = s4[1];
      float4 w0 = g4[0], w1 = g4[1];
      v0.x *= w0.x; v0.y *= w0.y; v0.z *= w0.z; v0.w *= w0.w;
      v1.x *= w1.x; v1.y *= w1.y; v1.z *= w1.z; v1.w *= w1.w;
      short8 hi, lo;
      split8(v0, v1, hi, lo);
      *(short8*)(Whh_hi + o8) = hi;
      *(short8*)(Whh_lo + o8) = lo;
    }
  }
  for (int g = idx; g < G_SZ; g += stride) {
    const float4* wr = (const float4*)(W_hh + (size_t)G_SZ * H_SZ + (size_t)g * H_SZ);
    const float4* gm = (const float4*)gamma_h;
    const float4* bt = (const float4*)beta_h;
    float sw = 0.f, sb = 0.f;
    for (int i = 0; i < H_SZ / 4; ++i) {
      float4 wv = wr[i], gv = gm[i], bv = bt[i];
      sw += wv.x * gv.x + wv.y * gv.y + wv.z * gv.z + wv.w * gv.w;
      sb += wv.x * bv.x + wv.y * bv.y + wv.z * bv.z + wv.w * bv.w;
    }
    SWp[g] = sw;
    Sbeta[g] = sb;
    bias[g] = b_ih[G_SZ + g] + b_hh[G_SZ + g];
  }
  for (int c = idx; c < 18432; c += stride) bar[c] = 0u;
}

// ---------------------------------------------------------------------------
// Phase 1: X[t][g][b] = A . Wih^T + bias (3-term double-bf16 MFMA)
// ---------------------------------------------------------------------------
#define K2_STR 56

__global__ __launch_bounds__(256) void xproj_kernel(
    const unsigned short* __restrict__ A_hi, const unsigned short* __restrict__ A_lo,
    const unsigned short* __restrict__ B_hi, const unsigned short* __restrict__ B_lo,
    const float* __restrict__ bias, void* __restrict__ Xout, int x_is_f32) {
  __shared__ float smemf[7168];
  unsigned short* AsH = (unsigned short*)smemf;
  unsigned short* AsL = AsH + 64 * K2_STR;
  unsigned short* BsH = AsL + 64 * K2_STR;
  unsigned short* BsL = BsH + 64 * K2_STR;

  int bid = blockIdx.x;
  int mchunk = bid / 384;
  int r = bid - mchunk * 384;
  int nb = r >> 3;
  int mb = (mchunk << 3) + (r & 7);
  int m0 = mb * 64, n0 = nb * 64;
  int tid = threadIdx.x;
  int w = tid >> 6, lane = tid & 63;
  int wm = w & 1, wn = w >> 1;
  int rs = tid >> 2, ks = (tid & 3) * 8;
  int lrow = lane & 15, lk = (lane >> 4) * 8;

  f32x4 acc[2][2] = {};
  const unsigned short* gA = A_hi + (size_t)(m0 + rs) * E_SZ + ks;
  const unsigned short* gAl = A_lo + (size_t)(m0 + rs) * E_SZ + ks;
  const unsigned short* gB = B_hi + (size_t)(n0 + rs) * E_SZ + ks;
  const unsigned short* gBl = B_lo + (size_t)(n0 + rs) * E_SZ + ks;
  short8 vah = *(const short8*)gA;
  short8 val = *(const short8*)gAl;
  short8 vbh = *(const short8*)gB;
  short8 vbl = *(const short8*)gBl;
  for (int kt = 0; kt < 24; ++kt) {
    __syncthreads();
    *(short8*)(AsH + rs * K2_STR + ks) = vah;
    *(short8*)(AsL + rs * K2_STR + ks) = val;
    *(short8*)(BsH + rs * K2_STR + ks) = vbh;
    *(short8*)(BsL + rs * K2_STR + ks) = vbl;
    __syncthreads();
    if (kt < 23) {
      int k0 = (kt + 1) * 32;
      vah = *(const short8*)(gA + k0);
      val = *(const short8*)(gAl + k0);
      vbh = *(const short8*)(gB + k0);
      vbl = *(const short8*)(gBl + k0);
    }
    bf16x8 ah0 = *(const bf16x8*)(AsH + (wm * 32 +      lrow) * K2_STR + lk);
    bf16x8 ah1 = *(const bf16x8*)(AsH + (wm * 32 + 16 + lrow) * K2_STR + lk);
    bf16x8 al0 = *(const bf16x8*)(AsL + (wm * 32 +      lrow) * K2_STR + lk);
    bf16x8 al1 = *(const bf16x8*)(AsL + (wm * 32 + 16 + lrow) * K2_STR + lk);
    bf16x8 bh0 = *(const bf16x8*)(BsH + (wn * 32 +      lrow) * K2_STR + lk);
    bf16x8 bh1 = *(const bf16x8*)(BsH + (wn * 32 + 16 + lrow) * K2_STR + lk);
    bf16x8 bl0 = *(const bf16x8*)(BsL + (wn * 32 +      lrow) * K2_STR + lk);
    bf16x8 bl1 = *(const bf16x8*)(BsL + (wn * 32 + 16 + lrow) * K2_STR + lk);
    acc[0][0] = __builtin_amdgcn_mfma_f32_16x16x32_bf16(ah0, bh0, acc[0][0], 0, 0, 0);
    acc[1][0] = __builtin_amdgcn_mfma_f32_16x16x32_bf16(ah1, bh0, acc[1][0], 0, 0, 0);
    acc[0][1] = __builtin_amdgcn_mfma_f32_16x16x32_bf16(ah0, bh1, acc[0][1], 0, 0, 0);
    acc[1][1] = __builtin_amdgcn_mfma_f32_16x16x32_bf16(ah1, bh1, acc[1][1], 0, 0, 0);
    acc[0][0] = __builtin_amdgcn_mfma_f32_16x16x32_bf16(al0, bh0, acc[0][0], 0, 0, 0);
    acc[1][0] = __builtin_amdgcn_mfma_f32_16x16x32_bf16(al1, bh0, acc[1][0], 0, 0, 0);
    acc[0][1] = __builtin_amdgcn_mfma_f32_16x16x32_bf16(al0, bh1, acc[0][1], 0, 0, 0);
    acc[1][1] = __builtin_amdgcn_mfma_f32_16x16x32_bf16(al1, bh1, acc[1][1], 0, 0, 0);
    acc[0][0] = __builtin_amdgcn_mfma_f32_16x16x32_bf16(ah0, bl0, acc[0][0], 0, 0, 0);
    acc[1][0] = __builtin_amdgcn_mfma_f32_16x16x32_bf16(ah1, bl0, acc[1][0], 0, 0, 0);
    acc[0][1] = __builtin_amdgcn_mfma_f32_16x16x32_bf16(ah0, bl1, acc[0][1], 0, 0, 0);
    acc[1][1] = __builtin_amdgcn_mfma_f32_16x16x32_bf16(ah1, bl1, acc[1][1], 0, 0, 0);
  }
  __syncthreads();
  float* Cs = smemf;
  int quad = lane >> 4;
#pragma unroll
  for (int mt = 0; mt < 2; ++mt)
#pragma unroll
    for (int nt = 0; nt < 2; ++nt) {
      int mloc = wm * 32 + mt * 16 + quad * 4;
      int nloc = wn * 32 + nt * 16 + lrow;
#pragma unroll
      for (int rr = 0; rr < 4; ++rr) Cs[nloc * 72 + mloc + rr] = acc[mt][nt][rr];
    }
  __syncthreads();
  int t = mb >> 1, bbase = (mb & 1) * 64;
#pragma unroll
  for (int rep = 0; rep < 2; ++rep) {
    int n = (tid >> 3) + rep * 32;
    int c = (tid & 7) * 8;
    float bv = bias[n0 + n];
    float v[8];
#pragma unroll
    for (int j = 0; j < 8; ++j) v[j] = Cs[n * 72 + c + j] + bv;
    size_t off = ((size_t)t * G_SZ + (n0 + n)) * B_SZ + bbase + c;
    if (x_is_f32) {
      float4* dst = (float4*)((float*)Xout + off);
      dst[0] = make_float4(v[0], v[1], v[2], v[3]);
      dst[1] = make_float4(v[4], v[5], v[6], v[7]);
    } else {
      short8 o;
#pragma unroll
      for (int j = 0; j < 8; ++j) o[j] = (short)f2bf(v[j]);
      *(short8*)((unsigned short*)Xout + off) = o;
    }
  }
}

// ---------------------------------------------------------------------------
// Phase 2: LSTM recurrence. 192 blocks = 96 jb x 2 rb (64 b-rows each).
// BOTH W' planes persistent in (dynamic) LDS -> zero per-step global W
// traffic (immune to the per-step L2 invalidate). X(t+1) prefetched into
// registers before the barrier.
// ---------------------------------------------------------------------------
__device__ __forceinline__ void gridbar(unsigned int* leaf, unsigned int* root,
                                        int idx, int sub) {
  __syncthreads();
  if (threadIdx.x == 0) {
    __builtin_amdgcn_fence(__ATOMIC_RELEASE, "agent");
    unsigned int old = __hip_atomic_fetch_add(&leaf[idx * 128 + sub * 16], 1u,
                                              __ATOMIC_RELAXED, __HIP_MEMORY_SCOPE_AGENT);
    if (old == 11u)
      __hip_atomic_fetch_add(&root[idx * 16], 1u,
                             __ATOMIC_RELAXED, __HIP_MEMORY_SCOPE_AGENT);
    while (__hip_atomic_load(&root[idx * 16], __ATOMIC_RELAXED,
                             __HIP_MEMORY_SCOPE_AGENT) < 8u)
      __builtin_amdgcn_s_sleep(2);
    __builtin_amdgcn_fence(__ATOMIC_ACQUIRE, "agent");
  }
  __syncthreads();
}

extern __shared__ char lstm_smem[];

__global__ __launch_bounds__(128) void lstm_kernel(
    const unsigned short* __restrict__ Whh_lo,
    const unsigned short* __restrict__ Whh_hi,
    const void* __restrict__ X, int x_is_f32,
    const float* __restrict__ SWp, const float* __restrict__ Sbeta,
    const float* __restrict__ gamma_h, const float* __restrict__ beta_h,
    const float* __restrict__ gamma_c, const float* __restrict__ beta_c,
    const int* __restrict__ lens,
    unsigned short* __restrict__ Hbuf, float* __restrict__ part,
    unsigned int* __restrict__ bar, float* __restrict__ out) {
  // dynamic LDS carve-up (112,896 B total)
  unsigned short* WtH = (unsigned short*)lstm_smem;   // 32*776
  unsigned short* WtL = WtH + 32 * 776;               // 32*776
  float* glds   = (float*)(WtL + 32 * 776);           // 4*8*72 = 2304
  float* pstat2 = glds + 2304;                        // 512
  float* rstat4 = pstat2 + 512;                       // 256
  float* rstat  = rstat4 + 256;                       // 256
  float* ghs = rstat + 256;                           // 8
  float* bhs = ghs + 8;
  float* gcs = bhs + 8;
  float* bcs = gcs + 8;

  int bidx = blockIdx.x;
  int jb = bidx % 96, rb = bidx / 96;
  int j0 = jb * 8, b0 = rb * 64;
  int tid = threadIdx.x;
  int w = tid >> 6, lane = tid & 63;
  int lrow = lane & 15, lkq = lane >> 4;
  int sub = jb / 12;
  unsigned int* leaf = bar;           // [idx*128 + sub*16]
  unsigned int* root = bar + 16384;   // [idx*16]

  // persistent W' hi+lo slices in LDS: row r <-> gate r>>3, jj r&7
  for (int c = tid; c < 3072; c += 128) {
    int row = c / 96, ko = (c - row * 96) * 8;
    size_t goff = ((size_t)((row >> 3) * H_SZ + j0 + (row & 7))) * H_SZ + ko;
    *(short8*)(&WtH[row * 776 + ko]) = *(const short8*)(Whh_hi + goff);
    *(short8*)(&WtL[row * 776 + ko]) = *(const short8*)(Whh_lo + goff);
  }
  if (tid < 8) {
    ghs[tid] = gamma_h[j0 + tid]; bhs[tid] = beta_h[j0 + tid];
    gcs[tid] = gamma_c[j0 + tid]; bcs[tid] = beta_c[j0 + tid];
  }

  int row = tid & 63;               // cell row
  int half = tid >> 6;              // 0/1
  int jjq = half * 4;               // jj quad base
  int mylen = lens[b0 + row];
  int myWrow = (w << 4) | lrow;     // 0..31 gate-row
  int gate4 = myWrow >> 3, jjl = myWrow & 7;
  int g_global = gate4 * H_SZ + j0 + jjl;
  float mySW = SWp[g_global];
  float mySb = Sbeta[g_global];
  const unsigned short* wbase = &WtH[(size_t)myWrow * 776];
  const unsigned short* wlob  = &WtL[(size_t)myWrow * 776];
  float c4[4], h4[4];
  float xv[4][4];
  __syncthreads();

  // ---------------- t = 0: gates = X(0), c0 = h0 = 0 ----------------
  {
    size_t xbase = ((size_t)0 * G_SZ + g_global) * B_SZ + b0 + lkq * 4;
#pragma unroll
    for (int mt = 0; mt < 4; ++mt) {
      float xr[4];
      if (x_is_f32) {
        float4 p = *(const float4*)((const float*)X + xbase + mt * 16);
        xr[0] = p.x; xr[1] = p.y; xr[2] = p.z; xr[3] = p.w;
      } else {
        ushort4 p = *(const ushort4*)((const unsigned short*)X + xbase + mt * 16);
        xr[0] = bf2f(p.x); xr[1] = bf2f(p.y); xr[2] = bf2f(p.z); xr[3] = bf2f(p.w);
      }
#pragma unroll
      for (int rr = 0; rr < 4; ++rr)
        glds[(gate4 * 8 + jjl) * 72 + mt * 16 + lkq * 4 + rr] = xr[rr];
    }
  }
  __syncthreads();
  {
    float ph = 0.f, ph2 = 0.f, pc = 0.f, pc2 = 0.f;
#pragma unroll
    for (int q = 0; q < 4; ++q) {
      int jj = jjq + q;
      float iv = glds[(0 * 8 + jj) * 72 + row];
      float gv = glds[(2 * 8 + jj) * 72 + row];
      float ov = glds[(3 * 8 + jj) * 72 + row];
      float si = 1.f / (1.f + expf(-iv));
      float so = 1.f / (1.f + expf(-ov));
      float cn = si * tanhf(gv);
      float hp = so * tanhf(cn);
      c4[q] = cn; h4[q] = hp;
      ph += hp; ph2 += hp * hp; pc += cn; pc2 += cn * cn;
    }
    size_t hx = (((size_t)0 * 128 + b0 + row) * 96 + jb) * 32 + jjq;
    ushort4 hiv, lov;
    hiv.x = f2bf(h4[0]); hiv.y = f2bf(h4[1]); hiv.z = f2bf(h4[2]); hiv.w = f2bf(h4[3]);
    lov.x = f2bf(h4[0] - bf2f(hiv.x)); lov.y = f2bf(h4[1] - bf2f(hiv.y));
    lov.z = f2bf(h4[2] - bf2f(hiv.z)); lov.w = f2bf(h4[3] - bf2f(hiv.w));
    *(ushort4*)&Hbuf[hx] = hiv;
    *(ushort4*)&Hbuf[hx + 8] = lov;
    *(f32x4*)&pstat2[(row * 2 + half) * 4] = f32x4{ph, ph2, pc, pc2};
  }
  __syncthreads();
  {
    int f = tid * 2;
    float2 v;
    v.x = pstat2[(f >> 2) * 8 + (f & 3)] + pstat2[(f >> 2) * 8 + 4 + (f & 3)];
    v.y = pstat2[((f + 1) >> 2) * 8 + ((f + 1) & 3)] +
          pstat2[((f + 1) >> 2) * 8 + 4 + ((f + 1) & 3)];
    *(float2*)&part[((size_t)(0 * 2 + rb) * 96 + jb) * 256 + f] = v;
  }
  // prefetch X(1) before barrier
  {
    size_t xbase = ((size_t)1 * G_SZ + g_global) * B_SZ + b0 + lkq * 4;
#pragma unroll
    for (int mt = 0; mt < 4; ++mt) {
      if (x_is_f32) {
        float4 p = *(const float4*)((const float*)X + xbase + mt * 16);
        xv[mt][0] = p.x; xv[mt][1] = p.y; xv[mt][2] = p.z; xv[mt][3] = p.w;
      } else {
        ushort4 p = *(const ushort4*)((const unsigned short*)X + xbase + mt * 16);
        xv[mt][0] = bf2f(p.x); xv[mt][1] = bf2f(p.y);
        xv[mt][2] = bf2f(p.z); xv[mt][3] = bf2f(p.w);
      }
    }
  }
  gridbar(leaf, root, 0 * 2 + rb, sub);

  // ---------------- t = 1 .. 63 ----------------
  for (int t = 1; t < T_LEN; ++t) {
    int pr = (t - 1) & 1, pw = t & 1;
    // GEMM: acc = h_pre(t-1) . W'^T (3-term hi/lo, W entirely in LDS)
    f32x4 acc[4] = {};
    {
      const unsigned short* hb[4];
#pragma unroll
      for (int mt = 0; mt < 4; ++mt)
        hb[mt] = Hbuf + ((size_t)pr * 128 + b0 + mt * 16 + lrow) * 3072;
#pragma unroll 4
      for (int kt = 0; kt < 24; ++kt) {
        int k0 = kt * 32 + lkq * 8;
        int co = (kt * 4 + lkq) * 32;
        bf16x8 wh = *(const bf16x8*)(wbase + k0);
        bf16x8 wl = *(const bf16x8*)(wlob + k0);
#pragma unroll
        for (int mt = 0; mt < 4; ++mt) {
          bf16x8 ah = *(const bf16x8*)(hb[mt] + co);
          bf16x8 al = *(const bf16x8*)(hb[mt] + co + 8);
          acc[mt] = __builtin_amdgcn_mfma_f32_16x16x32_bf16(ah, wh, acc[mt], 0, 0, 0);
          acc[mt] = __builtin_amdgcn_mfma_f32_16x16x32_bf16(al, wh, acc[mt], 0, 0, 0);
          acc[mt] = __builtin_amdgcn_mfma_f32_16x16x32_bf16(ah, wl, acc[mt], 0, 0, 0);
        }
      }
    }
    // reduce stats(t-1)
    float psum0 = 0.f, psum1 = 0.f;
    {
      const float* pb = part + ((size_t)((t - 1) * 2 + rb) * 96) * 256 + tid * 2;
#pragma unroll 8
      for (int j = 0; j < 96; ++j) {
        float2 v = *(const float2*)(pb + j * 256);
        psum0 += v.x; psum1 += v.y;
      }
    }
    {
      int f = tid * 2;
      rstat4[f] = psum0;
      rstat4[f + 1] = psum1;
    }
    __syncthreads();
    if (tid < 64) {
      f32x4 s = *(f32x4*)&rstat4[tid * 4];
      float muh = s[0] * (1.f / 768.f), muc = s[2] * (1.f / 768.f);
      float vh = s[1] * (1.f / 768.f) - muh * muh;
      float vc = s[3] * (1.f / 768.f) - muc * muc;
      float rh = rsqrtf(vh + LN_EPS), rc = rsqrtf(vc + LN_EPS);
      *(f32x4*)&rstat[tid * 4] = f32x4{rh, muh * rh, rc, muc * rc};
    }
    __syncthreads();
    // out write for told = t-1 (uses old h4 + rstat(t-1))
    {
      int told = t - 1;
      if (told == mylen - 1) {
        float2 rv = *(float2*)&rstat[row * 4];
#pragma unroll
        for (int q = 0; q < 4; ++q)
          out[(size_t)(b0 + row) * H_SZ + j0 + jjq + q] =
              (rv.x * h4[q] - rv.y) * ghs[jjq + q] + bhs[jjq + q];
      }
    }
    __syncthreads();
    // gates(t) = X + rh*acc - (muh*rh)*SW' + Sbeta
#pragma unroll
    for (int mt = 0; mt < 4; ++mt) {
#pragma unroll
      for (int rr = 0; rr < 4; ++rr) {
        int r2 = mt * 16 + lkq * 4 + rr;
        float2 rv = *(float2*)&rstat[r2 * 4];
        glds[(gate4 * 8 + jjl) * 72 + r2] =
            xv[mt][rr] + rv.x * acc[mt][rr] - rv.y * mySW + mySb;
      }
    }
    __syncthreads();
    // cell(t)
    {
      f32x4 rv = *(f32x4*)&rstat[row * 4];
      float ph = 0.f, ph2 = 0.f, pc = 0.f, pc2 = 0.f;
#pragma unroll
      for (int q = 0; q < 4; ++q) {
        int jj = jjq + q;
        float cprev = (rv[2] * c4[q] - rv[3]) * gcs[jj] + bcs[jj];   // LN(c(t-1))
        float iv = glds[(0 * 8 + jj) * 72 + row];
        float fv = glds[(1 * 8 + jj) * 72 + row];
        float gv = glds[(2 * 8 + jj) * 72 + row];
        float ov = glds[(3 * 8 + jj) * 72 + row];
        float si = 1.f / (1.f + expf(-iv));
        float sf = 1.f / (1.f + expf(-fv));
        float so = 1.f / (1.f + expf(-ov));
        float cn = sf * cprev + si * tanhf(gv);
        float hp = so * tanhf(cn);
        c4[q] = cn; h4[q] = hp;
        ph += hp; ph2 += hp * hp; pc += cn; pc2 += cn * cn;
      }
      size_t hx = (((size_t)pw * 128 + b0 + row) * 96 + jb) * 32 + jjq;
      ushort4 hiv, lov;
      hiv.x = f2bf(h4[0]); hiv.y = f2bf(h4[1]); hiv.z = f2bf(h4[2]); hiv.w = f2bf(h4[3]);
      lov.x = f2bf(h4[0] - bf2f(hiv.x)); lov.y = f2bf(h4[1] - bf2f(hiv.y));
      lov.z = f2bf(h4[2] - bf2f(hiv.z)); lov.w = f2bf(h4[3] - bf2f(hiv.w));
      *(ushort4*)&Hbuf[hx] = hiv;
      *(ushort4*)&Hbuf[hx + 8] = lov;
      *(f32x4*)&pstat2[(row * 2 + half) * 4] = f32x4{ph, ph2, pc, pc2};
    }
    __syncthreads();
    {
      int f = tid * 2;
      float2 v;
      v.x = pstat2[(f >> 2) * 8 + (f & 3)] + pstat2[(f >> 2) * 8 + 4 + (f & 3)];
      v.y = pstat2[((f + 1) >> 2) * 8 + ((f + 1) & 3)] +
            pstat2[((f + 1) >> 2) * 8 + 4 + ((f + 1) & 3)];
      *(float2*)&part[((size_t)(t * 2 + rb) * 96 + jb) * 256 + f] = v;
    }
    // prefetch X(t+1) before the barrier (step-independent data)
    if (t < T_LEN - 1) {
      size_t xbase = ((size_t)(t + 1) * G_SZ + g_global) * B_SZ + b0 + lkq * 4;
#pragma unroll
      for (int mt = 0; mt < 4; ++mt) {
        if (x_is_f32) {
          float4 p = *(const float4*)((const float*)X + xbase + mt * 16);
          xv[mt][0] = p.x; xv[mt][1] = p.y; xv[mt][2] = p.z; xv[mt][3] = p.w;
        } else {
          ushort4 p = *(const ushort4*)((const unsigned short*)X + xbase + mt * 16);
          xv[mt][0] = bf2f(p.x); xv[mt][1] = bf2f(p.y);
          xv[mt][2] = bf2f(p.z); xv[mt][3] = bf2f(p.w);
        }
      }
    }
    gridbar(leaf, root, t * 2 + rb, sub);
  }

  // ---------------- tail: rows with len == 64 ----------------
  {
    float psum0 = 0.f, psum1 = 0.f;
    const float* pb = part + ((size_t)(63 * 2 + rb) * 96) * 256 + tid * 2;
#pragma unroll 8
    for (int j = 0; j < 96; ++j) {
      float2 v = *(const float2*)(pb + j * 256);
      psum0 += v.x; psum1 += v.y;
    }
    rstat4[tid * 2] = psum0;
    rstat4[tid * 2 + 1] = psum1;
  }
  __syncthreads();
  if (tid < 64) {
    f32x4 s = *(f32x4*)&rstat4[tid * 4];
    float muh = s[0] * (1.f / 768.f);
    float vh = s[1] * (1.f / 768.f) - muh * muh;
    float rh = rsqrtf(vh + LN_EPS);
    rstat[tid * 4] = rh;
    rstat[tid * 4 + 1] = muh * rh;
  }
  __syncthreads();
  if (mylen == T_LEN) {
    float2 rv = *(float2*)&rstat[row * 4];
#pragma unroll
    for (int q = 0; q < 4; ++q)
      out[(size_t)(b0 + row) * H_SZ + j0 + jjq + q] =
          (rv.x * h4[q] - rv.y) * ghs[jjq + q] + bhs[jjq + q];
  }
}

#define LSTM_LDS_BYTES 112896

// ---------------------------------------------------------------------------
extern "C" void kernel_launch(void* const* d_in, const int* in_sizes, int n_in,
                              void* d_out, int out_size, void* d_ws, size_t ws_size,
                              hipStream_t stream) {
  const int*   msg     = (const int*)d_in[0];
  const int*   lens    = (const int*)d_in[1];
  const float* table   = (const float*)d_in[2];
  const float* W_ih    = (const float*)d_in[3];
  const float* W_hh    = (const float*)d_in[4];
  const float* b_ih    = (const float*)d_in[5];
  const float* b_hh    = (const float*)d_in[6];
  const float* gamma_h = (const float*)d_in[7];
  const float* beta_h  = (const float*)d_in[8];
  const float* gamma_c = (const float*)d_in[9];
  const float* beta_c  = (const float*)d_in[10];
  float* out = (float*)d_out;

  static int attr_done = 0;
  if (!attr_done) {
    hipFuncSetAttribute((const void*)lstm_kernel,
                        hipFuncAttributeMaxDynamicSharedMemorySize,
                        LSTM_LDS_BYTES);
    attr_done = 1;
  }

  size_t szA = (size_t)8192 * 768 * 2;
  size_t szW = (size_t)3072 * 768 * 2;
  size_t szF = 3072 * 4;
  size_t szH = (size_t)2 * 128 * 96 * 32 * 2;   // Hbuf: 1.5 MB
  size_t szBar = 18432 * 4;
  size_t rest = 2 * szA + 4 * szW + 3 * szF + szH + szBar;
  size_t xf32 = (size_t)64 * 3072 * 128 * 4;
  int x_is_f32 = (ws_size >= xf32 + rest) ? 1 : 0;

  char* p = (char*)d_ws;
  void* X = (void*)p;               p += x_is_f32 ? xf32 : (xf32 / 2);
  unsigned short* A_hi   = (unsigned short*)p; p += szA;
  unsigned short* A_lo   = (unsigned short*)p; p += szA;
  unsigned short* Wih_hi = (unsigned short*)p; p += szW;
  unsigned short* Wih_lo = (unsigned short*)p; p += szW;
  unsigned short* Whh_hi = (unsigned short*)p; p += szW;
  unsigned short* Whh_lo = (unsigned short*)p; p += szW;
  float* SWp   = (float*)p;         p += szF;
  float* Sbeta = (float*)p;         p += szF;
  float* bias  = (float*)p;         p += szF;
  unsigned short* Hbuf = (unsigned short*)p; p += szH;
  unsigned int* bar = (unsigned int*)p;      p += szBar;
  // part overlays A (xproj done before lstm): 128 slots x 96 x 256 x 4B = 12.6 MB
  float* part = (float*)A_hi;

  hipLaunchKernelGGL(prep_kernel, dim3(1024), dim3(256), 0, stream,
                     msg, table, W_ih, W_hh, b_ih, b_hh, gamma_h, beta_h,
                     A_hi, A_lo, Wih_hi, Wih_lo, Whh_hi, Whh_lo,
                     SWp, Sbeta, bias, bar);
  hipLaunchKernelGGL(xproj_kernel, dim3(6144), dim3(256), 0, stream,
                     A_hi, A_lo, Wih_hi, Wih_lo, bias, X, x_is_f32);

  void* kargs[] = { (void*)&Whh_lo, (void*)&Whh_hi, (void*)&X, (void*)&x_is_f32,
                    (void*)&SWp, (void*)&Sbeta,
                    (void*)&gamma_h, (void*)&beta_h, (void*)&gamma_c, (void*)&beta_c,
                    (void*)&lens, (void*)&Hbuf, (void*)&part,
                    (void*)&bar, (void*)&out };
  hipLaunchCooperativeKernel((void*)lstm_kernel, dim3(192), dim3(128), kargs,
                             LSTM_LDS_BYTES, stream);
}

// Round 6
// 1867.212 us; speedup vs baseline: 2.6914x; 1.1496x over previous
//
#include <hip/hip_runtime.h>
#include <stdint.h>

#define T_LEN 64
#define B_SZ  128
#define H_SZ  768
#define G_SZ  3072
#define E_SZ  768
#define LN_EPS 1e-5f

typedef __bf16 bf16x8 __attribute__((ext_vector_type(8)));
typedef float  f32x4  __attribute__((ext_vector_type(4)));
typedef short  short8 __attribute__((ext_vector_type(8)));

__device__ __forceinline__ float bf2f(unsigned short h) {
  unsigned int u = ((unsigned int)h) << 16;
  return __builtin_bit_cast(float, u);
}
__device__ __forceinline__ unsigned short f2bf(float f) {
  unsigned int u = __builtin_bit_cast(unsigned int, f);
  u += 0x7fffu + ((u >> 16) & 1u);   // RNE
  return (unsigned short)(u >> 16);
}
__device__ __forceinline__ void split8(float4 v0, float4 v1, short8& hi, short8& lo) {
  float v[8] = {v0.x, v0.y, v0.z, v0.w, v1.x, v1.y, v1.z, v1.w};
#pragma unroll
  for (int j = 0; j < 8; ++j) {
    unsigned short h = f2bf(v[j]);
    hi[j] = (short)h;
    lo[j] = (short)f2bf(v[j] - bf2f(h));
  }
}
// write-through store to the device coherence point (MALL) — no fence needed
__device__ __forceinline__ void st_wt(void* p, unsigned long long v) {
  __hip_atomic_store((unsigned long long*)p, v, __ATOMIC_RELAXED,
                     __HIP_MEMORY_SCOPE_AGENT);
}

// ---------------------------------------------------------------------------
// Prep
// ---------------------------------------------------------------------------
__global__ void prep_kernel(const int* __restrict__ msg,
                            const float* __restrict__ table,
                            const float* __restrict__ W_ih,
                            const float* __restrict__ W_hh,
                            const float* __restrict__ b_ih,
                            const float* __restrict__ b_hh,
                            const float* __restrict__ gamma_h,
                            const float* __restrict__ beta_h,
                            unsigned short* __restrict__ A_hi,
                            unsigned short* __restrict__ A_lo,
                            unsigned short* __restrict__ Wih_hi,
                            unsigned short* __restrict__ Wih_lo,
                            unsigned short* __restrict__ Whh_hi,
                            unsigned short* __restrict__ Whh_lo,
                            float* __restrict__ SWp,
                            float* __restrict__ Sbeta,
                            float* __restrict__ bias,
                            unsigned int* __restrict__ bar) {
  int idx = blockIdx.x * blockDim.x + threadIdx.x;
  int stride = gridDim.x * blockDim.x;
  // Embedding gather, n = t*128+b
  for (int c = idx; c < 8192 * 96; c += stride) {
    int n = c / 96;
    int ko = (c - n * 96) * 8;
    int b = n & 127, t = n >> 7;
    int m = msg[b * T_LEN + t];
    const float4* s4 = (const float4*)(table + (size_t)m * E_SZ + ko);
    short8 hi, lo;
    split8(s4[0], s4[1], hi, lo);
    *(short8*)(A_hi + (size_t)n * E_SZ + ko) = hi;
    *(short8*)(A_lo + (size_t)n * E_SZ + ko) = lo;
  }
  // Layer-1 weight splits. Whh scaled by gamma_h[j].
  for (int c = idx; c < G_SZ * E_SZ / 8; c += stride) {
    int o8 = c * 8;
    {
      const float4* s4 = (const float4*)(W_ih + (size_t)G_SZ * E_SZ + o8);
      short8 hi, lo;
      split8(s4[0], s4[1], hi, lo);
      *(short8*)(Wih_hi + o8) = hi;
      *(short8*)(Wih_lo + o8) = lo;
    }
    {
      int g = o8 / H_SZ;
      int j = o8 - g * H_SZ;
      const float4* s4 = (const float4*)(W_hh + (size_t)G_SZ * H_SZ + o8);
      const float4* g4 = (const float4*)(gamma_h + j);
      float4 v0 = s4[0], v1 = s4[1];
      float4 w0 = g4[0], w1 = g4[1];
      v0.x *= w0.x; v0.y *= w0.y; v0.z *= w0.z; v0.w *= w0.w;
      v1.x *= w1.x; v1.y *= w1.y; v1.z *= w1.z; v1.w *= w1.w;
      short8 hi, lo;
      split8(v0, v1, hi, lo);
      *(short8*)(Whh_hi + o8) = hi;
      *(short8*)(Whh_lo + o8) = lo;
    }
  }
  for (int g = idx; g < G_SZ; g += stride) {
    const float4* wr = (const float4*)(W_hh + (size_t)G_SZ * H_SZ + (size_t)g * H_SZ);
    const float4* gm = (const float4*)gamma_h;
    const float4* bt = (const float4*)beta_h;
    float sw = 0.f, sb = 0.f;
    for (int i = 0; i < H_SZ / 4; ++i) {
      float4 wv = wr[i], gv = gm[i], bv = bt[i];
      sw += wv.x * gv.x + wv.y * gv.y + wv.z * gv.z + wv.w * gv.w;
      sb += wv.x * bv.x + wv.y * bv.y + wv.z * bv.z + wv.w * bv.w;
    }
    SWp[g] = sw;
    Sbeta[g] = sb;
    bias[g] = b_ih[G_SZ + g] + b_hh[G_SZ + g];
  }
  for (int c = idx; c < 18432; c += stride) bar[c] = 0u;
}

// ---------------------------------------------------------------------------
// Phase 1: X[t][g][b] = A . Wih^T + bias (3-term double-bf16 MFMA)
// ---------------------------------------------------------------------------
#define K2_STR 56

__global__ __launch_bounds__(256) void xproj_kernel(
    const unsigned short* __restrict__ A_hi, const unsigned short* __restrict__ A_lo,
    const unsigned short* __restrict__ B_hi, const unsigned short* __restrict__ B_lo,
    const float* __restrict__ bias, void* __restrict__ Xout, int x_is_f32) {
  __shared__ float smemf[7168];
  unsigned short* AsH = (unsigned short*)smemf;
  unsigned short* AsL = AsH + 64 * K2_STR;
  unsigned short* BsH = AsL + 64 * K2_STR;
  unsigned short* BsL = BsH + 64 * K2_STR;

  int bid = blockIdx.x;
  int mchunk = bid / 384;
  int r = bid - mchunk * 384;
  int nb = r >> 3;
  int mb = (mchunk << 3) + (r & 7);
  int m0 = mb * 64, n0 = nb * 64;
  int tid = threadIdx.x;
  int w = tid >> 6, lane = tid & 63;
  int wm = w & 1, wn = w >> 1;
  int rs = tid >> 2, ks = (tid & 3) * 8;
  int lrow = lane & 15, lk = (lane >> 4) * 8;

  f32x4 acc[2][2] = {};
  const unsigned short* gA = A_hi + (size_t)(m0 + rs) * E_SZ + ks;
  const unsigned short* gAl = A_lo + (size_t)(m0 + rs) * E_SZ + ks;
  const unsigned short* gB = B_hi + (size_t)(n0 + rs) * E_SZ + ks;
  const unsigned short* gBl = B_lo + (size_t)(n0 + rs) * E_SZ + ks;
  short8 vah = *(const short8*)gA;
  short8 val = *(const short8*)gAl;
  short8 vbh = *(const short8*)gB;
  short8 vbl = *(const short8*)gBl;
  for (int kt = 0; kt < 24; ++kt) {
    __syncthreads();
    *(short8*)(AsH + rs * K2_STR + ks) = vah;
    *(short8*)(AsL + rs * K2_STR + ks) = val;
    *(short8*)(BsH + rs * K2_STR + ks) = vbh;
    *(short8*)(BsL + rs * K2_STR + ks) = vbl;
    __syncthreads();
    if (kt < 23) {
      int k0 = (kt + 1) * 32;
      vah = *(const short8*)(gA + k0);
      val = *(const short8*)(gAl + k0);
      vbh = *(const short8*)(gB + k0);
      vbl = *(const short8*)(gBl + k0);
    }
    bf16x8 ah0 = *(const bf16x8*)(AsH + (wm * 32 +      lrow) * K2_STR + lk);
    bf16x8 ah1 = *(const bf16x8*)(AsH + (wm * 32 + 16 + lrow) * K2_STR + lk);
    bf16x8 al0 = *(const bf16x8*)(AsL + (wm * 32 +      lrow) * K2_STR + lk);
    bf16x8 al1 = *(const bf16x8*)(AsL + (wm * 32 + 16 + lrow) * K2_STR + lk);
    bf16x8 bh0 = *(const bf16x8*)(BsH + (wn * 32 +      lrow) * K2_STR + lk);
    bf16x8 bh1 = *(const bf16x8*)(BsH + (wn * 32 + 16 + lrow) * K2_STR + lk);
    bf16x8 bl0 = *(const bf16x8*)(BsL + (wn * 32 +      lrow) * K2_STR + lk);
    bf16x8 bl1 = *(const bf16x8*)(BsL + (wn * 32 + 16 + lrow) * K2_STR + lk);
    acc[0][0] = __builtin_amdgcn_mfma_f32_16x16x32_bf16(ah0, bh0, acc[0][0], 0, 0, 0);
    acc[1][0] = __builtin_amdgcn_mfma_f32_16x16x32_bf16(ah1, bh0, acc[1][0], 0, 0, 0);
    acc[0][1] = __builtin_amdgcn_mfma_f32_16x16x32_bf16(ah0, bh1, acc[0][1], 0, 0, 0);
    acc[1][1] = __builtin_amdgcn_mfma_f32_16x16x32_bf16(ah1, bh1, acc[1][1], 0, 0, 0);
    acc[0][0] = __builtin_amdgcn_mfma_f32_16x16x32_bf16(al0, bh0, acc[0][0], 0, 0, 0);
    acc[1][0] = __builtin_amdgcn_mfma_f32_16x16x32_bf16(al1, bh0, acc[1][0], 0, 0, 0);
    acc[0][1] = __builtin_amdgcn_mfma_f32_16x16x32_bf16(al0, bh1, acc[0][1], 0, 0, 0);
    acc[1][1] = __builtin_amdgcn_mfma_f32_16x16x32_bf16(al1, bh1, acc[1][1], 0, 0, 0);
    acc[0][0] = __builtin_amdgcn_mfma_f32_16x16x32_bf16(ah0, bl0, acc[0][0], 0, 0, 0);
    acc[1][0] = __builtin_amdgcn_mfma_f32_16x16x32_bf16(ah1, bl0, acc[1][0], 0, 0, 0);
    acc[0][1] = __builtin_amdgcn_mfma_f32_16x16x32_bf16(ah0, bl1, acc[0][1], 0, 0, 0);
    acc[1][1] = __builtin_amdgcn_mfma_f32_16x16x32_bf16(ah1, bl1, acc[1][1], 0, 0, 0);
  }
  __syncthreads();
  float* Cs = smemf;
  int quad = lane >> 4;
#pragma unroll
  for (int mt = 0; mt < 2; ++mt)
#pragma unroll
    for (int nt = 0; nt < 2; ++nt) {
      int mloc = wm * 32 + mt * 16 + quad * 4;
      int nloc = wn * 32 + nt * 16 + lrow;
#pragma unroll
      for (int rr = 0; rr < 4; ++rr) Cs[nloc * 72 + mloc + rr] = acc[mt][nt][rr];
    }
  __syncthreads();
  int t = mb >> 1, bbase = (mb & 1) * 64;
#pragma unroll
  for (int rep = 0; rep < 2; ++rep) {
    int n = (tid >> 3) + rep * 32;
    int c = (tid & 7) * 8;
    float bv = bias[n0 + n];
    float v[8];
#pragma unroll
    for (int j = 0; j < 8; ++j) v[j] = Cs[n * 72 + c + j] + bv;
    size_t off = ((size_t)t * G_SZ + (n0 + n)) * B_SZ + bbase + c;
    if (x_is_f32) {
      float4* dst = (float4*)((float*)Xout + off);
      dst[0] = make_float4(v[0], v[1], v[2], v[3]);
      dst[1] = make_float4(v[4], v[5], v[6], v[7]);
    } else {
      short8 o;
#pragma unroll
      for (int j = 0; j < 8; ++j) o[j] = (short)f2bf(v[j]);
      *(short8*)((unsigned short*)Xout + off) = o;
    }
  }
}

// ---------------------------------------------------------------------------
// Phase 2: LSTM recurrence, FENCE-FREE coherence:
//  - cross-block data written via relaxed agent atomics (write-through to MALL)
//  - every cross-block buffer address is used once (Hbuf rotates over 64 planes,
//    part rotates over 128 slots) -> plain cached reads always cold-miss and
//    fetch the fresh line; no buffer_inv / buffer_wbl2 ever executed.
// ---------------------------------------------------------------------------
__device__ __forceinline__ void gridbar(unsigned int* leaf, unsigned int* root,
                                        int idx, int sub) {
  __syncthreads();   // drains each thread's vmcnt -> all wt-stores at MALL
  if (threadIdx.x == 0) {
    asm volatile("" ::: "memory");
    unsigned int old = __hip_atomic_fetch_add(&leaf[idx * 128 + sub * 16], 1u,
                                              __ATOMIC_RELAXED, __HIP_MEMORY_SCOPE_AGENT);
    if (old == 11u)
      __hip_atomic_fetch_add(&root[idx * 16], 1u,
                             __ATOMIC_RELAXED, __HIP_MEMORY_SCOPE_AGENT);
    while (__hip_atomic_load(&root[idx * 16], __ATOMIC_RELAXED,
                             __HIP_MEMORY_SCOPE_AGENT) < 8u)
      __builtin_amdgcn_s_sleep(2);
    asm volatile("" ::: "memory");
  }
  __syncthreads();
}

extern __shared__ char lstm_smem[];

__global__ __launch_bounds__(128) void lstm_kernel(
    const unsigned short* __restrict__ Whh_lo,
    const unsigned short* __restrict__ Whh_hi,
    const void* __restrict__ X, int x_is_f32,
    const float* __restrict__ SWp, const float* __restrict__ Sbeta,
    const float* __restrict__ gamma_h, const float* __restrict__ beta_h,
    const float* __restrict__ gamma_c, const float* __restrict__ beta_c,
    const int* __restrict__ lens,
    unsigned short* __restrict__ Hbuf, float* __restrict__ part,
    unsigned int* __restrict__ bar, float* __restrict__ out) {
  // dynamic LDS carve-up (112,896 B total)
  unsigned short* WtH = (unsigned short*)lstm_smem;   // 32*776
  unsigned short* WtL = WtH + 32 * 776;               // 32*776
  float* glds   = (float*)(WtL + 32 * 776);           // 4*8*72 = 2304
  float* pstat2 = glds + 2304;                        // 512
  float* rstat4 = pstat2 + 512;                       // 256
  float* rstat  = rstat4 + 256;                       // 256
  float* ghs = rstat + 256;                           // 8
  float* bhs = ghs + 8;
  float* gcs = bhs + 8;
  float* bcs = gcs + 8;

  int bidx = blockIdx.x;
  int jb = bidx % 96, rb = bidx / 96;
  int j0 = jb * 8, b0 = rb * 64;
  int tid = threadIdx.x;
  int w = tid >> 6, lane = tid & 63;
  int lrow = lane & 15, lkq = lane >> 4;
  int sub = jb / 12;
  unsigned int* leaf = bar;           // [idx*128 + sub*16]
  unsigned int* root = bar + 16384;   // [idx*16]

  // persistent W' hi+lo slices in LDS: row r <-> gate r>>3, jj r&7
  for (int c = tid; c < 3072; c += 128) {
    int row = c / 96, ko = (c - row * 96) * 8;
    size_t goff = ((size_t)((row >> 3) * H_SZ + j0 + (row & 7))) * H_SZ + ko;
    *(short8*)(&WtH[row * 776 + ko]) = *(const short8*)(Whh_hi + goff);
    *(short8*)(&WtL[row * 776 + ko]) = *(const short8*)(Whh_lo + goff);
  }
  if (tid < 8) {
    ghs[tid] = gamma_h[j0 + tid]; bhs[tid] = beta_h[j0 + tid];
    gcs[tid] = gamma_c[j0 + tid]; bcs[tid] = beta_c[j0 + tid];
  }

  int row = tid & 63;               // cell row
  int half = tid >> 6;              // 0/1
  int jjq = half * 4;               // jj quad base
  int mylen = lens[b0 + row];
  int myWrow = (w << 4) | lrow;     // 0..31 gate-row
  int gate4 = myWrow >> 3, jjl = myWrow & 7;
  int g_global = gate4 * H_SZ + j0 + jjl;
  float mySW = SWp[g_global];
  float mySb = Sbeta[g_global];
  const unsigned short* wbase = &WtH[(size_t)myWrow * 776];
  const unsigned short* wlob  = &WtL[(size_t)myWrow * 776];
  float c4[4], h4[4];
  float xv[4][4];
  __syncthreads();

  // ---------------- t = 0: gates = X(0), c0 = h0 = 0 ----------------
  {
    size_t xbase = ((size_t)0 * G_SZ + g_global) * B_SZ + b0 + lkq * 4;
#pragma unroll
    for (int mt = 0; mt < 4; ++mt) {
      float xr[4];
      if (x_is_f32) {
        float4 p = *(const float4*)((const float*)X + xbase + mt * 16);
        xr[0] = p.x; xr[1] = p.y; xr[2] = p.z; xr[3] = p.w;
      } else {
        ushort4 p = *(const ushort4*)((const unsigned short*)X + xbase + mt * 16);
        xr[0] = bf2f(p.x); xr[1] = bf2f(p.y); xr[2] = bf2f(p.z); xr[3] = bf2f(p.w);
      }
#pragma unroll
      for (int rr = 0; rr < 4; ++rr)
        glds[(gate4 * 8 + jjl) * 72 + mt * 16 + lkq * 4 + rr] = xr[rr];
    }
  }
  __syncthreads();
  {
    float ph = 0.f, ph2 = 0.f, pc = 0.f, pc2 = 0.f;
#pragma unroll
    for (int q = 0; q < 4; ++q) {
      int jj = jjq + q;
      float iv = glds[(0 * 8 + jj) * 72 + row];
      float gv = glds[(2 * 8 + jj) * 72 + row];
      float ov = glds[(3 * 8 + jj) * 72 + row];
      float si = 1.f / (1.f + expf(-iv));
      float so = 1.f / (1.f + expf(-ov));
      float cn = si * tanhf(gv);
      float hp = so * tanhf(cn);
      c4[q] = cn; h4[q] = hp;
      ph += hp; ph2 += hp * hp; pc += cn; pc2 += cn * cn;
    }
    size_t hx = (((size_t)0 * 128 + b0 + row) * 96 + jb) * 32 + jjq;
    ushort4 hiv, lov;
    hiv.x = f2bf(h4[0]); hiv.y = f2bf(h4[1]); hiv.z = f2bf(h4[2]); hiv.w = f2bf(h4[3]);
    lov.x = f2bf(h4[0] - bf2f(hiv.x)); lov.y = f2bf(h4[1] - bf2f(hiv.y));
    lov.z = f2bf(h4[2] - bf2f(hiv.z)); lov.w = f2bf(h4[3] - bf2f(hiv.w));
    st_wt(&Hbuf[hx], __builtin_bit_cast(unsigned long long, hiv));
    st_wt(&Hbuf[hx + 8], __builtin_bit_cast(unsigned long long, lov));
    *(f32x4*)&pstat2[(row * 2 + half) * 4] = f32x4{ph, ph2, pc, pc2};
  }
  __syncthreads();
  {
    int f = tid * 2;
    float2 v;
    v.x = pstat2[(f >> 2) * 8 + (f & 3)] + pstat2[(f >> 2) * 8 + 4 + (f & 3)];
    v.y = pstat2[((f + 1) >> 2) * 8 + ((f + 1) & 3)] +
          pstat2[((f + 1) >> 2) * 8 + 4 + ((f + 1) & 3)];
    st_wt(&part[((size_t)(0 * 2 + rb) * 96 + jb) * 256 + f],
          __builtin_bit_cast(unsigned long long, v));
  }
  // prefetch X(1) before barrier
  {
    size_t xbase = ((size_t)1 * G_SZ + g_global) * B_SZ + b0 + lkq * 4;
#pragma unroll
    for (int mt = 0; mt < 4; ++mt) {
      if (x_is_f32) {
        float4 p = *(const float4*)((const float*)X + xbase + mt * 16);
        xv[mt][0] = p.x; xv[mt][1] = p.y; xv[mt][2] = p.z; xv[mt][3] = p.w;
      } else {
        ushort4 p = *(const ushort4*)((const unsigned short*)X + xbase + mt * 16);
        xv[mt][0] = bf2f(p.x); xv[mt][1] = bf2f(p.y);
        xv[mt][2] = bf2f(p.z); xv[mt][3] = bf2f(p.w);
      }
    }
  }
  gridbar(leaf, root, 0 * 2 + rb, sub);

  // ---------------- t = 1 .. 63 ----------------
  for (int t = 1; t < T_LEN; ++t) {
    // GEMM: acc = h_pre(t-1) . W'^T (3-term hi/lo; Hbuf plane t-1, cold reads)
    f32x4 acc[4] = {};
    {
      const unsigned short* hb[4];
#pragma unroll
      for (int mt = 0; mt < 4; ++mt)
        hb[mt] = Hbuf + ((size_t)(t - 1) * 128 + b0 + mt * 16 + lrow) * 3072;
#pragma unroll 4
      for (int kt = 0; kt < 24; ++kt) {
        int k0 = kt * 32 + lkq * 8;
        int co = (kt * 4 + lkq) * 32;
        bf16x8 wh = *(const bf16x8*)(wbase + k0);
        bf16x8 wl = *(const bf16x8*)(wlob + k0);
#pragma unroll
        for (int mt = 0; mt < 4; ++mt) {
          bf16x8 ah = *(const bf16x8*)(hb[mt] + co);
          bf16x8 al = *(const bf16x8*)(hb[mt] + co + 8);
          acc[mt] = __builtin_amdgcn_mfma_f32_16x16x32_bf16(ah, wh, acc[mt], 0, 0, 0);
          acc[mt] = __builtin_amdgcn_mfma_f32_16x16x32_bf16(al, wh, acc[mt], 0, 0, 0);
          acc[mt] = __builtin_amdgcn_mfma_f32_16x16x32_bf16(ah, wl, acc[mt], 0, 0, 0);
        }
      }
    }
    // reduce stats(t-1) (slot rotated by t -> cold reads)
    float psum0 = 0.f, psum1 = 0.f;
    {
      const float* pb = part + ((size_t)((t - 1) * 2 + rb) * 96) * 256 + tid * 2;
#pragma unroll 8
      for (int j = 0; j < 96; ++j) {
        float2 v = *(const float2*)(pb + j * 256);
        psum0 += v.x; psum1 += v.y;
      }
    }
    {
      int f = tid * 2;
      rstat4[f] = psum0;
      rstat4[f + 1] = psum1;
    }
    __syncthreads();
    if (tid < 64) {
      f32x4 s = *(f32x4*)&rstat4[tid * 4];
      float muh = s[0] * (1.f / 768.f), muc = s[2] * (1.f / 768.f);
      float vh = s[1] * (1.f / 768.f) - muh * muh;
      float vc = s[3] * (1.f / 768.f) - muc * muc;
      float rh = rsqrtf(vh + LN_EPS), rc = rsqrtf(vc + LN_EPS);
      *(f32x4*)&rstat[tid * 4] = f32x4{rh, muh * rh, rc, muc * rc};
    }
    __syncthreads();
    // out write for told = t-1 (uses old h4 + rstat(t-1))
    {
      int told = t - 1;
      if (told == mylen - 1) {
        float2 rv = *(float2*)&rstat[row * 4];
#pragma unroll
        for (int q = 0; q < 4; ++q)
          out[(size_t)(b0 + row) * H_SZ + j0 + jjq + q] =
              (rv.x * h4[q] - rv.y) * ghs[jjq + q] + bhs[jjq + q];
      }
    }
    __syncthreads();
    // gates(t) = X + rh*acc - (muh*rh)*SW' + Sbeta
#pragma unroll
    for (int mt = 0; mt < 4; ++mt) {
#pragma unroll
      for (int rr = 0; rr < 4; ++rr) {
        int r2 = mt * 16 + lkq * 4 + rr;
        float2 rv = *(float2*)&rstat[r2 * 4];
        glds[(gate4 * 8 + jjl) * 72 + r2] =
            xv[mt][rr] + rv.x * acc[mt][rr] - rv.y * mySW + mySb;
      }
    }
    __syncthreads();
    // cell(t)
    {
      f32x4 rv = *(f32x4*)&rstat[row * 4];
      float ph = 0.f, ph2 = 0.f, pc = 0.f, pc2 = 0.f;
#pragma unroll
      for (int q = 0; q < 4; ++q) {
        int jj = jjq + q;
        float cprev = (rv[2] * c4[q] - rv[3]) * gcs[jj] + bcs[jj];   // LN(c(t-1))
        float iv = glds[(0 * 8 + jj) * 72 + row];
        float fv = glds[(1 * 8 + jj) * 72 + row];
        float gv = glds[(2 * 8 + jj) * 72 + row];
        float ov = glds[(3 * 8 + jj) * 72 + row];
        float si = 1.f / (1.f + expf(-iv));
        float sf = 1.f / (1.f + expf(-fv));
        float so = 1.f / (1.f + expf(-ov));
        float cn = sf * cprev + si * tanhf(gv);
        float hp = so * tanhf(cn);
        c4[q] = cn; h4[q] = hp;
        ph += hp; ph2 += hp * hp; pc += cn; pc2 += cn * cn;
      }
      size_t hx = (((size_t)t * 128 + b0 + row) * 96 + jb) * 32 + jjq;
      ushort4 hiv, lov;
      hiv.x = f2bf(h4[0]); hiv.y = f2bf(h4[1]); hiv.z = f2bf(h4[2]); hiv.w = f2bf(h4[3]);
      lov.x = f2bf(h4[0] - bf2f(hiv.x)); lov.y = f2bf(h4[1] - bf2f(hiv.y));
      lov.z = f2bf(h4[2] - bf2f(hiv.z)); lov.w = f2bf(h4[3] - bf2f(hiv.w));
      st_wt(&Hbuf[hx], __builtin_bit_cast(unsigned long long, hiv));
      st_wt(&Hbuf[hx + 8], __builtin_bit_cast(unsigned long long, lov));
      *(f32x4*)&pstat2[(row * 2 + half) * 4] = f32x4{ph, ph2, pc, pc2};
    }
    __syncthreads();
    {
      int f = tid * 2;
      float2 v;
      v.x = pstat2[(f >> 2) * 8 + (f & 3)] + pstat2[(f >> 2) * 8 + 4 + (f & 3)];
      v.y = pstat2[((f + 1) >> 2) * 8 + ((f + 1) & 3)] +
            pstat2[((f + 1) >> 2) * 8 + 4 + ((f + 1) & 3)];
      st_wt(&part[((size_t)(t * 2 + rb) * 96 + jb) * 256 + f],
            __builtin_bit_cast(unsigned long long, v));
    }
    // prefetch X(t+1) before the barrier (step-independent data)
    if (t < T_LEN - 1) {
      size_t xbase = ((size_t)(t + 1) * G_SZ + g_global) * B_SZ + b0 + lkq * 4;
#pragma unroll
      for (int mt = 0; mt < 4; ++mt) {
        if (x_is_f32) {
          float4 p = *(const float4*)((const float*)X + xbase + mt * 16);
          xv[mt][0] = p.x; xv[mt][1] = p.y; xv[mt][2] = p.z; xv[mt][3] = p.w;
        } else {
          ushort4 p = *(const ushort4*)((const unsigned short*)X + xbase + mt * 16);
          xv[mt][0] = bf2f(p.x); xv[mt][1] = bf2f(p.y);
          xv[mt][2] = bf2f(p.z); xv[mt][3] = bf2f(p.w);
        }
      }
    }
    gridbar(leaf, root, t * 2 + rb, sub);
  }

  // ---------------- tail: rows with len == 64 ----------------
  {
    float psum0 = 0.f, psum1 = 0.f;
    const float* pb = part + ((size_t)(63 * 2 + rb) * 96) * 256 + tid * 2;
#pragma unroll 8
    for (int j = 0; j < 96; ++j) {
      float2 v = *(const float2*)(pb + j * 256);
      psum0 += v.x; psum1 += v.y;
    }
    rstat4[tid * 2] = psum0;
    rstat4[tid * 2 + 1] = psum1;
  }
  __syncthreads();
  if (tid < 64) {
    f32x4 s = *(f32x4*)&rstat4[tid * 4];
    float muh = s[0] * (1.f / 768.f);
    float vh = s[1] * (1.f / 768.f) - muh * muh;
    float rh = rsqrtf(vh + LN_EPS);
    rstat[tid * 4] = rh;
    rstat[tid * 4 + 1] = muh * rh;
  }
  __syncthreads();
  if (mylen == T_LEN) {
    float2 rv = *(float2*)&rstat[row * 4];
#pragma unroll
    for (int q = 0; q < 4; ++q)
      out[(size_t)(b0 + row) * H_SZ + j0 + jjq + q] =
          (rv.x * h4[q] - rv.y) * ghs[jjq + q] + bhs[jjq + q];
  }
}

#define LSTM_LDS_BYTES 112896

// ---------------------------------------------------------------------------
extern "C" void kernel_launch(void* const* d_in, const int* in_sizes, int n_in,
                              void* d_out, int out_size, void* d_ws, size_t ws_size,
                              hipStream_t stream) {
  const int*   msg     = (const int*)d_in[0];
  const int*   lens    = (const int*)d_in[1];
  const float* table   = (const float*)d_in[2];
  const float* W_ih    = (const float*)d_in[3];
  const float* W_hh    = (const float*)d_in[4];
  const float* b_ih    = (const float*)d_in[5];
  const float* b_hh    = (const float*)d_in[6];
  const float* gamma_h = (const float*)d_in[7];
  const float* beta_h  = (const float*)d_in[8];
  const float* gamma_c = (const float*)d_in[9];
  const float* beta_c  = (const float*)d_in[10];
  float* out = (float*)d_out;

  static int attr_done = 0;
  if (!attr_done) {
    hipFuncSetAttribute((const void*)lstm_kernel,
                        hipFuncAttributeMaxDynamicSharedMemorySize,
                        LSTM_LDS_BYTES);
    attr_done = 1;
  }

  size_t szA = (size_t)8192 * 768 * 2;
  size_t szW = (size_t)3072 * 768 * 2;
  size_t szF = 3072 * 4;
  size_t szH = (size_t)T_LEN * 128 * 96 * 32 * 2;   // Hbuf: 64 rotating planes, 50.3 MB
  size_t szBar = 18432 * 4;
  size_t rest = 2 * szA + 4 * szW + 3 * szF + szH + szBar;
  size_t xf32 = (size_t)64 * 3072 * 128 * 4;
  int x_is_f32 = (ws_size >= xf32 + rest) ? 1 : 0;

  char* p = (char*)d_ws;
  void* X = (void*)p;               p += x_is_f32 ? xf32 : (xf32 / 2);
  unsigned short* A_hi   = (unsigned short*)p; p += szA;
  unsigned short* A_lo   = (unsigned short*)p; p += szA;
  unsigned short* Wih_hi = (unsigned short*)p; p += szW;
  unsigned short* Wih_lo = (unsigned short*)p; p += szW;
  unsigned short* Whh_hi = (unsigned short*)p; p += szW;
  unsigned short* Whh_lo = (unsigned short*)p; p += szW;
  float* SWp   = (float*)p;         p += szF;
  float* Sbeta = (float*)p;         p += szF;
  float* bias  = (float*)p;         p += szF;
  unsigned short* Hbuf = (unsigned short*)p; p += szH;
  unsigned int* bar = (unsigned int*)p;      p += szBar;
  // part overlays A (xproj done before lstm): 128 slots x 96 x 256 x 4B = 12.6 MB
  float* part = (float*)A_hi;

  hipLaunchKernelGGL(prep_kernel, dim3(1024), dim3(256), 0, stream,
                     msg, table, W_ih, W_hh, b_ih, b_hh, gamma_h, beta_h,
                     A_hi, A_lo, Wih_hi, Wih_lo, Whh_hi, Whh_lo,
                     SWp, Sbeta, bias, bar);
  hipLaunchKernelGGL(xproj_kernel, dim3(6144), dim3(256), 0, stream,
                     A_hi, A_lo, Wih_hi, Wih_lo, bias, X, x_is_f32);

  void* kargs[] = { (void*)&Whh_lo, (void*)&Whh_hi, (void*)&X, (void*)&x_is_f32,
                    (void*)&SWp, (void*)&Sbeta,
                    (void*)&gamma_h, (void*)&beta_h, (void*)&gamma_c, (void*)&beta_c,
                    (void*)&lens, (void*)&Hbuf, (void*)&part,
                    (void*)&bar, (void*)&out };
  hipLaunchCooperativeKernel((void*)lstm_kernel, dim3(192), dim3(128), kargs,
                             LSTM_LDS_BYTES, stream);
}